// Round 1
// baseline (266.800 us; speedup 1.0000x reference)
//
#include <hip/hip_runtime.h>

typedef __attribute__((ext_vector_type(8))) short short8;
typedef __attribute__((ext_vector_type(4))) short short4v;
typedef __attribute__((ext_vector_type(4))) float f32x4;

constexpr int SL = 2048, BS = 4, D = 512, H = 8, NH = 64;
constexpr int M_ROWS = SL * BS;   // 8192
constexpr float SCALE = 0.125f;   // 1/sqrt(64)

__device__ __forceinline__ unsigned short f2bf(float f) {
  union { float f; unsigned u; } v; v.f = f;
  unsigned r = v.u + 0x7FFFu + ((v.u >> 16) & 1u);
  return (unsigned short)(r >> 16);
}

// ---------------------------------------------------------------------------
// GEMM: C[M x 512] = A[M x 512] @ W[512 x 512] + bias, 128x128 tiles, 4 waves,
// mfma_f32_16x16x32_bf16, f32->bf16 conversion during LDS staging.
// ---------------------------------------------------------------------------
template <bool A_BF16, bool OUT_BF16>
__device__ __forceinline__ void gemm_body(const void* __restrict__ Ap,
                                          const float* __restrict__ W,
                                          const float* __restrict__ bias,
                                          void* __restrict__ Outp) {
  constexpr int TK = 64, LDT = 72;  // +8 pad breaks bank alignment
  __shared__ __align__(16) unsigned short a_lds[128 * LDT];
  __shared__ __align__(16) unsigned short b_lds[128 * LDT];

  const int tid = threadIdx.x;
  const int brow = blockIdx.x * 128;
  const int bcol = blockIdx.y * 128;
  const int lane = tid & 63;
  const int wid = tid >> 6;
  const int wr = (wid >> 1) * 64;   // wave row offset in tile
  const int wc = (wid & 1) * 64;    // wave col offset in tile
  const int r = lane & 15;
  const int g = lane >> 4;

  f32x4 acc[4][4];
#pragma unroll
  for (int m = 0; m < 4; ++m)
#pragma unroll
    for (int n = 0; n < 4; ++n) acc[m][n] = f32x4{0.f, 0.f, 0.f, 0.f};

  for (int kt = 0; kt < D; kt += TK) {
    // ---- stage A tile [128 x 64] ----
    if (A_BF16) {
      const unsigned short* A = (const unsigned short*)Ap;
#pragma unroll
      for (int i = 0; i < 4; ++i) {
        int e = tid * 8 + i * 2048;
        int row = e >> 6, col = e & 63;
        short8 v = *reinterpret_cast<const short8*>(&A[(brow + row) * D + kt + col]);
        *reinterpret_cast<short8*>(&a_lds[row * LDT + col]) = v;
      }
    } else {
      const float* A = (const float*)Ap;
#pragma unroll
      for (int i = 0; i < 8; ++i) {
        int e = tid * 4 + i * 1024;
        int row = e >> 6, col = e & 63;
        f32x4 v = *reinterpret_cast<const f32x4*>(&A[(brow + row) * D + kt + col]);
        short4v sv;
        sv[0] = (short)f2bf(v[0]); sv[1] = (short)f2bf(v[1]);
        sv[2] = (short)f2bf(v[2]); sv[3] = (short)f2bf(v[3]);
        *reinterpret_cast<short4v*>(&a_lds[row * LDT + col]) = sv;
      }
    }
    // ---- stage B tile [64 x 128] transposed -> b_lds[n][k] ----
#pragma unroll
    for (int i = 0; i < 8; ++i) {
      int e = tid * 4 + i * 1024;
      int k = e >> 7, n = e & 127;
      f32x4 v = *reinterpret_cast<const f32x4*>(&W[(kt + k) * D + bcol + n]);
#pragma unroll
      for (int j = 0; j < 4; ++j) b_lds[(n + j) * LDT + k] = f2bf(v[j]);
    }
    __syncthreads();

#pragma unroll
    for (int kk = 0; kk < TK; kk += 32) {
      short8 af[4], bfr[4];
#pragma unroll
      for (int m = 0; m < 4; ++m)
        af[m] = *reinterpret_cast<const short8*>(&a_lds[(wr + m * 16 + r) * LDT + kk + g * 8]);
#pragma unroll
      for (int n = 0; n < 4; ++n)
        bfr[n] = *reinterpret_cast<const short8*>(&b_lds[(wc + n * 16 + r) * LDT + kk + g * 8]);
#pragma unroll
      for (int m = 0; m < 4; ++m)
#pragma unroll
        for (int n = 0; n < 4; ++n)
          acc[m][n] = __builtin_amdgcn_mfma_f32_16x16x32_bf16(af[m], bfr[n], acc[m][n], 0, 0, 0);
    }
    __syncthreads();
  }

  // ---- epilogue: D layout col=lane&15, row=(lane>>4)*4+reg (m89/m91) ----
#pragma unroll
  for (int m = 0; m < 4; ++m)
#pragma unroll
    for (int n = 0; n < 4; ++n) {
      int gcol = bcol + wc + n * 16 + r;
      float bv = bias[gcol];
#pragma unroll
      for (int rr = 0; rr < 4; ++rr) {
        int grow = brow + wr + m * 16 + g * 4 + rr;
        float val = acc[m][n][rr] + bv;
        if (OUT_BF16)
          ((unsigned short*)Outp)[grow * D + gcol] = f2bf(val);
        else
          ((float*)Outp)[grow * D + gcol] = val;
      }
    }
}

__global__ __launch_bounds__(256) void qkv_gemm(
    const float* __restrict__ x0, const float* __restrict__ x1, const float* __restrict__ x2,
    const float* __restrict__ w0, const float* __restrict__ w1, const float* __restrict__ w2,
    const float* __restrict__ b0, const float* __restrict__ b1, const float* __restrict__ b2,
    unsigned short* __restrict__ outbase) {
  int z = blockIdx.z;
  const float* X = z == 0 ? x0 : (z == 1 ? x1 : x2);
  const float* W = z == 0 ? w0 : (z == 1 ? w1 : w2);
  const float* B = z == 0 ? b0 : (z == 1 ? b1 : b2);
  unsigned short* O = outbase + (size_t)z * M_ROWS * D;
  gemm_body<false, true>(X, W, B, O);
}

__global__ __launch_bounds__(256) void gemm_oproj(
    const unsigned short* __restrict__ A, const float* __restrict__ W,
    const float* __restrict__ B, float* __restrict__ Outp) {
  gemm_body<true, false>(A, W, B, Outp);
}

// ---------------------------------------------------------------------------
// Flash-style causal attention. Grid (SL/64, BS, H). 4 waves/block, each wave
// owns 16 q-rows. K tile and V^T tile in LDS; online softmax in registers
// (wave-parallel via shfl_xor over the 16-lane column group); P goes through
// per-wave LDS to reach MFMA A-fragment layout.
// ---------------------------------------------------------------------------
__global__ __launch_bounds__(256) void flash_attn(
    const unsigned short* __restrict__ Q, const unsigned short* __restrict__ K,
    const unsigned short* __restrict__ V, unsigned short* __restrict__ O) {
  constexpr int LDT = 72;
  __shared__ __align__(16) unsigned short k_lds[64 * LDT];
  __shared__ __align__(16) unsigned short v_ldsT[64 * LDT];  // [nh][key]
  __shared__ __align__(16) unsigned short p_lds[4 * 16 * LDT];

  const int tid = threadIdx.x;
  const int qt = blockIdx.x, b = blockIdx.y, h = blockIdx.z;
  const int w = tid >> 6, lane = tid & 63;
  const int r = lane & 15, g = lane >> 4;

  // Q fragments for this wave's 16 rows, kept in registers (K dim = NH = 64)
  short8 qf[2];
  {
    int qrow = qt * 64 + w * 16 + r;
    const unsigned short* qp = &Q[(qrow * BS + b) * D + h * NH];
    qf[0] = *reinterpret_cast<const short8*>(&qp[g * 8]);
    qf[1] = *reinterpret_cast<const short8*>(&qp[32 + g * 8]);
  }

  f32x4 o_acc[4];
#pragma unroll
  for (int n = 0; n < 4; ++n) o_acc[n] = f32x4{0.f, 0.f, 0.f, 0.f};
  float m_run[4], l_run[4];
#pragma unroll
  for (int rr = 0; rr < 4; ++rr) { m_run[rr] = -1e30f; l_run[rr] = 0.f; }

  for (int kt = 0; kt <= qt; ++kt) {
    // ---- stage K tile [64 keys x 64 nh] and V^T tile [64 nh x 64 keys] ----
#pragma unroll
    for (int i = 0; i < 2; ++i) {
      int e = tid * 8 + i * 2048;
      int key = e >> 6, col = e & 63;
      int gidx = ((kt * 64 + key) * BS + b) * D + h * NH + col;
      short8 kv = *reinterpret_cast<const short8*>(&K[gidx]);
      *reinterpret_cast<short8*>(&k_lds[key * LDT + col]) = kv;
      short8 vv = *reinterpret_cast<const short8*>(&V[gidx]);
#pragma unroll
      for (int j = 0; j < 8; ++j)
        v_ldsT[(col + j) * LDT + key] = (unsigned short)vv[j];
    }
    __syncthreads();

    // ---- S = Q K^T  (4 acc tiles of 16x16 keys) ----
    f32x4 s_acc[4];
#pragma unroll
    for (int n = 0; n < 4; ++n) s_acc[n] = f32x4{0.f, 0.f, 0.f, 0.f};
#pragma unroll
    for (int n = 0; n < 4; ++n)
#pragma unroll
      for (int kk = 0; kk < 2; ++kk) {
        short8 kf = *reinterpret_cast<const short8*>(
            &k_lds[(n * 16 + r) * LDT + kk * 32 + g * 8]);
        s_acc[n] = __builtin_amdgcn_mfma_f32_16x16x32_bf16(qf[kk], kf, s_acc[n], 0, 0, 0);
      }

    // ---- scale + causal mask ----
#pragma unroll
    for (int n = 0; n < 4; ++n) {
      int kg = kt * 64 + n * 16 + r;
#pragma unroll
      for (int rr = 0; rr < 4; ++rr) {
        int qg = qt * 64 + w * 16 + g * 4 + rr;
        float s = s_acc[n][rr] * SCALE;
        s_acc[n][rr] = (kg > qg) ? -1e30f : s;
      }
    }

    // ---- online softmax (per row rr; row group = 16 lanes sharing g) ----
#pragma unroll
    for (int rr = 0; rr < 4; ++rr) {
      float mx = fmaxf(fmaxf(s_acc[0][rr], s_acc[1][rr]),
                       fmaxf(s_acc[2][rr], s_acc[3][rr]));
      mx = fmaxf(mx, __shfl_xor(mx, 1));
      mx = fmaxf(mx, __shfl_xor(mx, 2));
      mx = fmaxf(mx, __shfl_xor(mx, 4));
      mx = fmaxf(mx, __shfl_xor(mx, 8));
      float mnew = fmaxf(m_run[rr], mx);
      float sf = __expf(m_run[rr] - mnew);
      m_run[rr] = mnew;
      float psum = 0.f;
#pragma unroll
      for (int n = 0; n < 4; ++n) {
        float p = __expf(s_acc[n][rr] - mnew);
        s_acc[n][rr] = p;
        psum += p;
      }
      psum += __shfl_xor(psum, 1);
      psum += __shfl_xor(psum, 2);
      psum += __shfl_xor(psum, 4);
      psum += __shfl_xor(psum, 8);
      l_run[rr] = l_run[rr] * sf + psum;
#pragma unroll
      for (int n = 0; n < 4; ++n) o_acc[n][rr] *= sf;
    }

    // ---- P (D-layout) -> per-wave LDS -> A-fragment layout ----
#pragma unroll
    for (int n = 0; n < 4; ++n)
#pragma unroll
      for (int rr = 0; rr < 4; ++rr)
        p_lds[(w * 16 + g * 4 + rr) * LDT + n * 16 + r] = f2bf(s_acc[n][rr]);
    asm volatile("s_waitcnt lgkmcnt(0)" ::: "memory");  // wave-internal RAW

    // ---- O += P @ V ----
#pragma unroll
    for (int kk = 0; kk < 2; ++kk) {
      short8 pf = *reinterpret_cast<const short8*>(
          &p_lds[(w * 16 + r) * LDT + kk * 32 + g * 8]);
#pragma unroll
      for (int n = 0; n < 4; ++n) {
        short8 vf = *reinterpret_cast<const short8*>(
            &v_ldsT[(n * 16 + r) * LDT + kk * 32 + g * 8]);
        o_acc[n] = __builtin_amdgcn_mfma_f32_16x16x32_bf16(pf, vf, o_acc[n], 0, 0, 0);
      }
    }
    __syncthreads();
  }

  // ---- normalize + store bf16 ----
#pragma unroll
  for (int n = 0; n < 4; ++n)
#pragma unroll
    for (int rr = 0; rr < 4; ++rr) {
      int qrow = qt * 64 + w * 16 + g * 4 + rr;
      float val = o_acc[n][rr] / l_run[rr];
      O[(qrow * BS + b) * D + h * NH + n * 16 + r] = f2bf(val);
    }
}

// ---------------------------------------------------------------------------
extern "C" void kernel_launch(void* const* d_in, const int* in_sizes, int n_in,
                              void* d_out, int out_size, void* d_ws, size_t ws_size,
                              hipStream_t stream) {
  const float* x  = (const float*)d_in[0];
  const float* kx = (const float*)d_in[1];
  const float* vx = (const float*)d_in[2];
  const float* Wq = (const float*)d_in[3];
  const float* bq = (const float*)d_in[4];
  const float* Wk = (const float*)d_in[5];
  const float* bk = (const float*)d_in[6];
  const float* Wv = (const float*)d_in[7];
  const float* bv = (const float*)d_in[8];
  const float* Wo = (const float*)d_in[9];
  const float* bo = (const float*)d_in[10];

  // workspace layout (bf16): q | k | v | attn_out, 8 MB each = 32 MB total
  unsigned short* ws = (unsigned short*)d_ws;
  unsigned short* qb = ws;
  unsigned short* kb = ws + (size_t)M_ROWS * D;
  unsigned short* vb = ws + (size_t)M_ROWS * D * 2;
  unsigned short* ab = ws + (size_t)M_ROWS * D * 3;

  dim3 blk(256);
  qkv_gemm<<<dim3(64, 4, 3), blk, 0, stream>>>(x, kx, vx, Wq, Wk, Wv, bq, bk, bv, ws);
  flash_attn<<<dim3(32, 4, 8), blk, 0, stream>>>(qb, kb, vb, ab);
  gemm_oproj<<<dim3(64, 4, 1), blk, 0, stream>>>(ab, Wo, bo, (float*)d_out);
}

// Round 2
// 219.487 us; speedup vs baseline: 1.2156x; 1.2156x over previous
//
#include <hip/hip_runtime.h>

typedef __attribute__((ext_vector_type(8))) short short8;
typedef __attribute__((ext_vector_type(4))) short short4v;
typedef __attribute__((ext_vector_type(4))) float f32x4;

constexpr int SL = 2048, BS = 4, D = 512, H = 8, NH = 64;
constexpr int M_ROWS = SL * BS;   // 8192
constexpr float SCALE = 0.125f;   // 1/sqrt(64)

__device__ __forceinline__ unsigned short f2bf(float f) {
  union { float f; unsigned u; } v; v.f = f;
  unsigned r = v.u + 0x7FFFu + ((v.u >> 16) & 1u);
  return (unsigned short)(r >> 16);
}

// ---------------------------------------------------------------------------
// GEMM: C[M x 512] = A[M x 512] @ W[512 x 512] + bias, 128x128 tiles, 4 waves,
// mfma_f32_16x16x32_bf16. OUT_MODE: 0 = f32 row-major, 1 = bf16 row-major,
// 2 = bf16 V^T layout [b][h][nh][s].
// ---------------------------------------------------------------------------
template <bool A_BF16, int OUT_MODE>
__device__ __forceinline__ void gemm_body(const void* __restrict__ Ap,
                                          const float* __restrict__ W,
                                          const float* __restrict__ bias,
                                          void* __restrict__ Outp) {
  constexpr int TK = 64, LDT = 72;
  __shared__ __align__(16) unsigned short a_lds[128 * LDT];
  __shared__ __align__(16) unsigned short b_lds[128 * LDT];

  const int tid = threadIdx.x;
  const int brow = blockIdx.x * 128;
  const int bcol = blockIdx.y * 128;
  const int lane = tid & 63;
  const int wid = tid >> 6;
  const int wr = (wid >> 1) * 64;
  const int wc = (wid & 1) * 64;
  const int r = lane & 15;
  const int g = lane >> 4;

  f32x4 acc[4][4];
#pragma unroll
  for (int m = 0; m < 4; ++m)
#pragma unroll
    for (int n = 0; n < 4; ++n) acc[m][n] = f32x4{0.f, 0.f, 0.f, 0.f};

  for (int kt = 0; kt < D; kt += TK) {
    if (A_BF16) {
      const unsigned short* A = (const unsigned short*)Ap;
#pragma unroll
      for (int i = 0; i < 4; ++i) {
        int e = tid * 8 + i * 2048;
        int row = e >> 6, col = e & 63;
        short8 v = *reinterpret_cast<const short8*>(&A[(brow + row) * D + kt + col]);
        *reinterpret_cast<short8*>(&a_lds[row * LDT + col]) = v;
      }
    } else {
      const float* A = (const float*)Ap;
#pragma unroll
      for (int i = 0; i < 8; ++i) {
        int e = tid * 4 + i * 1024;
        int row = e >> 6, col = e & 63;
        f32x4 v = *reinterpret_cast<const f32x4*>(&A[(brow + row) * D + kt + col]);
        short4v sv;
        sv[0] = (short)f2bf(v[0]); sv[1] = (short)f2bf(v[1]);
        sv[2] = (short)f2bf(v[2]); sv[3] = (short)f2bf(v[3]);
        *reinterpret_cast<short4v*>(&a_lds[row * LDT + col]) = sv;
      }
    }
#pragma unroll
    for (int i = 0; i < 8; ++i) {
      int e = tid * 4 + i * 1024;
      int k = e >> 7, n = e & 127;
      f32x4 v = *reinterpret_cast<const f32x4*>(&W[(kt + k) * D + bcol + n]);
#pragma unroll
      for (int j = 0; j < 4; ++j) b_lds[(n + j) * LDT + k] = f2bf(v[j]);
    }
    __syncthreads();

#pragma unroll
    for (int kk = 0; kk < TK; kk += 32) {
      short8 af[4], bfr[4];
#pragma unroll
      for (int m = 0; m < 4; ++m)
        af[m] = *reinterpret_cast<const short8*>(&a_lds[(wr + m * 16 + r) * LDT + kk + g * 8]);
#pragma unroll
      for (int n = 0; n < 4; ++n)
        bfr[n] = *reinterpret_cast<const short8*>(&b_lds[(wc + n * 16 + r) * LDT + kk + g * 8]);
      __builtin_amdgcn_s_setprio(1);
#pragma unroll
      for (int m = 0; m < 4; ++m)
#pragma unroll
        for (int n = 0; n < 4; ++n)
          acc[m][n] = __builtin_amdgcn_mfma_f32_16x16x32_bf16(af[m], bfr[n], acc[m][n], 0, 0, 0);
      __builtin_amdgcn_s_setprio(0);
    }
    __syncthreads();
  }

  // D layout: col=lane&15, row=(lane>>4)*4+reg (m89/m91)
#pragma unroll
  for (int m = 0; m < 4; ++m)
#pragma unroll
    for (int n = 0; n < 4; ++n) {
      int gcol = bcol + wc + n * 16 + r;
      float bv = bias[gcol];
#pragma unroll
      for (int rr = 0; rr < 4; ++rr) {
        int grow = brow + wr + m * 16 + g * 4 + rr;
        float val = acc[m][n][rr] + bv;
        if (OUT_MODE == 0) {
          ((float*)Outp)[grow * D + gcol] = val;
        } else if (OUT_MODE == 1) {
          ((unsigned short*)Outp)[grow * D + gcol] = f2bf(val);
        } else {
          int s = grow >> 2, bb = grow & 3;
          int hh = gcol >> 6, nh = gcol & 63;
          ((unsigned short*)Outp)[(((size_t)bb * H + hh) * NH + nh) * SL + s] = f2bf(val);
        }
      }
    }
}

__global__ __launch_bounds__(256) void qkv_gemm(
    const float* __restrict__ x0, const float* __restrict__ x1, const float* __restrict__ x2,
    const float* __restrict__ w0, const float* __restrict__ w1, const float* __restrict__ w2,
    const float* __restrict__ b0, const float* __restrict__ b1, const float* __restrict__ b2,
    unsigned short* __restrict__ outbase) {
  int z = blockIdx.z;
  const float* X = z == 0 ? x0 : (z == 1 ? x1 : x2);
  const float* W = z == 0 ? w0 : (z == 1 ? w1 : w2);
  const float* B = z == 0 ? b0 : (z == 1 ? b1 : b2);
  unsigned short* O = outbase + (size_t)z * M_ROWS * D;
  if (z == 2)
    gemm_body<false, 2>(X, W, B, O);
  else
    gemm_body<false, 1>(X, W, B, O);
}

__global__ __launch_bounds__(256) void gemm_oproj(
    const unsigned short* __restrict__ A, const float* __restrict__ W,
    const float* __restrict__ B, float* __restrict__ Outp) {
  gemm_body<true, 0>(A, W, B, Outp);
}

// ---------------------------------------------------------------------------
// Flash-style causal attention. Grid (16, BS, H), qt launched DESCENDING.
// 4 waves/block; each wave owns 32 q-rows (128/block). K tile [64 key][64 nh]
// and V^T tile [64 nh][64 key] in XOR-swizzled LDS (col ^= (row&7)<<3, granule
// = 8 shorts = 16B). V^T comes pre-transposed from the V-GEMM epilogue.
// Online softmax in registers; P via per-wave swizzled LDS.
// ---------------------------------------------------------------------------
__global__ __launch_bounds__(256) void flash_attn(
    const unsigned short* __restrict__ Q, const unsigned short* __restrict__ K,
    const unsigned short* __restrict__ Vt, unsigned short* __restrict__ O) {
  __shared__ __align__(16) unsigned short k_lds[64 * 64];
  __shared__ __align__(16) unsigned short v_lds[64 * 64];
  __shared__ __align__(16) unsigned short p_lds[4 * 32 * 64];

  const int tid = threadIdx.x;
  const int qt = (int)gridDim.x - 1 - (int)blockIdx.x;  // long blocks first
  const int b = blockIdx.y, h = blockIdx.z;
  const int w = tid >> 6, lane = tid & 63;
  const int r = lane & 15, g = lane >> 4;
  const int qbase = qt * 128;

  // Q fragments: wave's 32 rows, K dim = 64
  short8 qf[2][2];
#pragma unroll
  for (int ms = 0; ms < 2; ++ms)
#pragma unroll
    for (int kk = 0; kk < 2; ++kk) {
      int qrow = qbase + w * 32 + ms * 16 + r;
      qf[ms][kk] = *reinterpret_cast<const short8*>(
          &Q[((size_t)qrow * BS + b) * D + h * NH + kk * 32 + g * 8]);
    }

  f32x4 o_acc[2][4];
  float m_run[2][4], l_run[2][4];
#pragma unroll
  for (int ms = 0; ms < 2; ++ms) {
#pragma unroll
    for (int n = 0; n < 4; ++n) o_acc[ms][n] = f32x4{0.f, 0.f, 0.f, 0.f};
#pragma unroll
    for (int rr = 0; rr < 4; ++rr) { m_run[ms][rr] = -1e30f; l_run[ms][rr] = 0.f; }
  }

  const int kt_last = 2 * qt + 1;
  for (int kt = 0; kt <= kt_last; ++kt) {
    // ---- stage K [key][nh] and V^T [nh][key], both swizzled ----
#pragma unroll
    for (int i = 0; i < 2; ++i) {
      int row = (tid >> 3) + i * 32;       // key for K, nh for V^T
      int c = (tid & 7) * 8;
      short8 kv = *reinterpret_cast<const short8*>(
          &K[(((size_t)kt * 64 + row) * BS + b) * D + h * NH + c]);
      *reinterpret_cast<short8*>(&k_lds[row * 64 + (c ^ ((row & 7) << 3))]) = kv;
      short8 vv = *reinterpret_cast<const short8*>(
          &Vt[(((size_t)b * H + h) * NH + row) * SL + kt * 64 + c]);
      *reinterpret_cast<short8*>(&v_lds[row * 64 + (c ^ ((row & 7) << 3))]) = vv;
    }
    __syncthreads();

    // ---- S = Q K^T : 2x4 tiles of 16x16 ----
    f32x4 s_acc[2][4];
#pragma unroll
    for (int ms = 0; ms < 2; ++ms)
#pragma unroll
      for (int n = 0; n < 4; ++n) s_acc[ms][n] = f32x4{0.f, 0.f, 0.f, 0.f};
#pragma unroll
    for (int kk = 0; kk < 2; ++kk) {
      short8 kf[4];
#pragma unroll
      for (int n = 0; n < 4; ++n)
        kf[n] = *reinterpret_cast<const short8*>(
            &k_lds[(n * 16 + r) * 64 + ((kk * 32 + g * 8) ^ ((r & 7) << 3))]);
      __builtin_amdgcn_s_setprio(1);
#pragma unroll
      for (int ms = 0; ms < 2; ++ms)
#pragma unroll
        for (int n = 0; n < 4; ++n)
          s_acc[ms][n] = __builtin_amdgcn_mfma_f32_16x16x32_bf16(qf[ms][kk], kf[n], s_acc[ms][n], 0, 0, 0);
      __builtin_amdgcn_s_setprio(0);
    }

    // ---- scale + causal mask + online softmax ----
#pragma unroll
    for (int ms = 0; ms < 2; ++ms) {
#pragma unroll
      for (int rr = 0; rr < 4; ++rr) {
        int qg = qbase + w * 32 + ms * 16 + g * 4 + rr;
#pragma unroll
        for (int n = 0; n < 4; ++n) {
          int kg = kt * 64 + n * 16 + r;
          float s = s_acc[ms][n][rr] * SCALE;
          s_acc[ms][n][rr] = (kg > qg) ? -1e30f : s;
        }
        float mx = fmaxf(fmaxf(s_acc[ms][0][rr], s_acc[ms][1][rr]),
                         fmaxf(s_acc[ms][2][rr], s_acc[ms][3][rr]));
        mx = fmaxf(mx, __shfl_xor(mx, 1));
        mx = fmaxf(mx, __shfl_xor(mx, 2));
        mx = fmaxf(mx, __shfl_xor(mx, 4));
        mx = fmaxf(mx, __shfl_xor(mx, 8));
        float mnew = fmaxf(m_run[ms][rr], mx);
        float sf = __expf(m_run[ms][rr] - mnew);
        m_run[ms][rr] = mnew;
        float psum = 0.f;
#pragma unroll
        for (int n = 0; n < 4; ++n) {
          float p = __expf(s_acc[ms][n][rr] - mnew);
          s_acc[ms][n][rr] = p;
          psum += p;
        }
        psum += __shfl_xor(psum, 1);
        psum += __shfl_xor(psum, 2);
        psum += __shfl_xor(psum, 4);
        psum += __shfl_xor(psum, 8);
        l_run[ms][rr] = l_run[ms][rr] * sf + psum;
#pragma unroll
        for (int n = 0; n < 4; ++n) o_acc[ms][n][rr] *= sf;
      }
    }

    // ---- P (D-layout) -> per-wave swizzled LDS ----
#pragma unroll
    for (int ms = 0; ms < 2; ++ms)
#pragma unroll
      for (int n = 0; n < 4; ++n)
#pragma unroll
        for (int rr = 0; rr < 4; ++rr) {
          int prow = ms * 16 + g * 4 + rr;
          p_lds[w * 2048 + prow * 64 + ((n * 16 + r) ^ ((prow & 7) << 3))] =
              f2bf(s_acc[ms][n][rr]);
        }
    asm volatile("s_waitcnt lgkmcnt(0)" ::: "memory");

    // ---- O += P @ V ----
#pragma unroll
    for (int kk = 0; kk < 2; ++kk) {
      short8 pf[2], vf[4];
#pragma unroll
      for (int ms = 0; ms < 2; ++ms)
        pf[ms] = *reinterpret_cast<const short8*>(
            &p_lds[w * 2048 + (ms * 16 + r) * 64 + ((kk * 32 + g * 8) ^ ((r & 7) << 3))]);
#pragma unroll
      for (int n = 0; n < 4; ++n)
        vf[n] = *reinterpret_cast<const short8*>(
            &v_lds[(n * 16 + r) * 64 + ((kk * 32 + g * 8) ^ ((r & 7) << 3))]);
      __builtin_amdgcn_s_setprio(1);
#pragma unroll
      for (int ms = 0; ms < 2; ++ms)
#pragma unroll
        for (int n = 0; n < 4; ++n)
          o_acc[ms][n] = __builtin_amdgcn_mfma_f32_16x16x32_bf16(pf[ms], vf[n], o_acc[ms][n], 0, 0, 0);
      __builtin_amdgcn_s_setprio(0);
    }
    __syncthreads();
  }

  // ---- normalize + store bf16 ----
#pragma unroll
  for (int ms = 0; ms < 2; ++ms)
#pragma unroll
    for (int n = 0; n < 4; ++n)
#pragma unroll
      for (int rr = 0; rr < 4; ++rr) {
        int qrow = qbase + w * 32 + ms * 16 + g * 4 + rr;
        float val = o_acc[ms][n][rr] / l_run[ms][rr];
        O[((size_t)qrow * BS + b) * D + h * NH + n * 16 + r] = f2bf(val);
      }
}

// ---------------------------------------------------------------------------
extern "C" void kernel_launch(void* const* d_in, const int* in_sizes, int n_in,
                              void* d_out, int out_size, void* d_ws, size_t ws_size,
                              hipStream_t stream) {
  const float* x  = (const float*)d_in[0];
  const float* kx = (const float*)d_in[1];
  const float* vx = (const float*)d_in[2];
  const float* Wq = (const float*)d_in[3];
  const float* bq = (const float*)d_in[4];
  const float* Wk = (const float*)d_in[5];
  const float* bk = (const float*)d_in[6];
  const float* Wv = (const float*)d_in[7];
  const float* bv = (const float*)d_in[8];
  const float* Wo = (const float*)d_in[9];
  const float* bo = (const float*)d_in[10];

  // workspace (bf16): q | k | v^T | attn_out, 8 MB each
  unsigned short* ws = (unsigned short*)d_ws;
  unsigned short* qb = ws;
  unsigned short* kb = ws + (size_t)M_ROWS * D;
  unsigned short* vtb = ws + (size_t)M_ROWS * D * 2;
  unsigned short* ab = ws + (size_t)M_ROWS * D * 3;

  dim3 blk(256);
  qkv_gemm<<<dim3(64, 4, 3), blk, 0, stream>>>(x, kx, vx, Wq, Wk, Wv, bq, bk, bv, ws);
  flash_attn<<<dim3(16, 4, 8), blk, 0, stream>>>(qb, kb, vtb, ab);
  gemm_oproj<<<dim3(64, 4, 1), blk, 0, stream>>>(ab, Wo, bo, (float*)d_out);
}

// Round 3
// 165.031 us; speedup vs baseline: 1.6167x; 1.3300x over previous
//
#include <hip/hip_runtime.h>

typedef __attribute__((ext_vector_type(8))) short short8;
typedef __attribute__((ext_vector_type(4))) short short4v;
typedef __attribute__((ext_vector_type(4))) float f32x4;
typedef __attribute__((ext_vector_type(2))) unsigned int uint2v;

constexpr int SL = 2048, BS = 4, D = 512, H = 8, NH = 64;
constexpr int M_ROWS = SL * BS;   // 8192
constexpr float SCALE = 0.125f;   // 1/sqrt(64)
constexpr float LOG2E = 1.44269504088896340736f;

__device__ __forceinline__ unsigned short f2bf(float f) {
  union { float f; unsigned u; } v; v.f = f;
  unsigned r = v.u + 0x7FFFu + ((v.u >> 16) & 1u);
  return (unsigned short)(r >> 16);
}

__device__ __forceinline__ unsigned cvt_pk_bf16(float a, float b) {
  unsigned r;
  asm("v_cvt_pk_bf16_f32 %0, %1, %2" : "=v"(r) : "v"(a), "v"(b));
  return r;
}

__device__ __forceinline__ float fast_exp2(float x) {
  float r;
  asm("v_exp_f32 %0, %1" : "=v"(r) : "v"(x));
  return r;
}

// ---------------------------------------------------------------------------
// GEMM: C[M x 512] = (A[M x 512] @ W[512 x 512] + bias) * scale.
// 128x128 tiles, 4 waves, mfma_f32_16x16x32_bf16.
// OUT_MODE: 0 = f32 row-major, 1 = bf16 row-major, 2 = bf16 V^T [b][h][nh][s].
// ---------------------------------------------------------------------------
template <bool A_BF16, int OUT_MODE>
__device__ __forceinline__ void gemm_body(const void* __restrict__ Ap,
                                          const float* __restrict__ W,
                                          const float* __restrict__ bias,
                                          void* __restrict__ Outp, float scale) {
  constexpr int TK = 64, LDT = 72;
  __shared__ __align__(16) unsigned short a_lds[128 * LDT];
  __shared__ __align__(16) unsigned short b_lds[128 * LDT];

  const int tid = threadIdx.x;
  const int brow = blockIdx.x * 128;
  const int bcol = blockIdx.y * 128;
  const int lane = tid & 63;
  const int wid = tid >> 6;
  const int wr = (wid >> 1) * 64;
  const int wc = (wid & 1) * 64;
  const int r = lane & 15;
  const int g = lane >> 4;

  f32x4 acc[4][4];
#pragma unroll
  for (int m = 0; m < 4; ++m)
#pragma unroll
    for (int n = 0; n < 4; ++n) acc[m][n] = f32x4{0.f, 0.f, 0.f, 0.f};

  for (int kt = 0; kt < D; kt += TK) {
    if (A_BF16) {
      const unsigned short* A = (const unsigned short*)Ap;
#pragma unroll
      for (int i = 0; i < 4; ++i) {
        int e = tid * 8 + i * 2048;
        int row = e >> 6, col = e & 63;
        short8 v = *reinterpret_cast<const short8*>(&A[(brow + row) * D + kt + col]);
        *reinterpret_cast<short8*>(&a_lds[row * LDT + col]) = v;
      }
    } else {
      const float* A = (const float*)Ap;
#pragma unroll
      for (int i = 0; i < 8; ++i) {
        int e = tid * 4 + i * 1024;
        int row = e >> 6, col = e & 63;
        f32x4 v = *reinterpret_cast<const f32x4*>(&A[(brow + row) * D + kt + col]);
        short4v sv;
        sv[0] = (short)f2bf(v[0]); sv[1] = (short)f2bf(v[1]);
        sv[2] = (short)f2bf(v[2]); sv[3] = (short)f2bf(v[3]);
        *reinterpret_cast<short4v*>(&a_lds[row * LDT + col]) = sv;
      }
    }
#pragma unroll
    for (int i = 0; i < 8; ++i) {
      int e = tid * 4 + i * 1024;
      int k = e >> 7, n = e & 127;
      f32x4 v = *reinterpret_cast<const f32x4*>(&W[(kt + k) * D + bcol + n]);
#pragma unroll
      for (int j = 0; j < 4; ++j) b_lds[(n + j) * LDT + k] = f2bf(v[j]);
    }
    __syncthreads();

#pragma unroll
    for (int kk = 0; kk < TK; kk += 32) {
      short8 af[4], bfr[4];
#pragma unroll
      for (int m = 0; m < 4; ++m)
        af[m] = *reinterpret_cast<const short8*>(&a_lds[(wr + m * 16 + r) * LDT + kk + g * 8]);
#pragma unroll
      for (int n = 0; n < 4; ++n)
        bfr[n] = *reinterpret_cast<const short8*>(&b_lds[(wc + n * 16 + r) * LDT + kk + g * 8]);
      __builtin_amdgcn_s_setprio(1);
#pragma unroll
      for (int m = 0; m < 4; ++m)
#pragma unroll
        for (int n = 0; n < 4; ++n)
          acc[m][n] = __builtin_amdgcn_mfma_f32_16x16x32_bf16(af[m], bfr[n], acc[m][n], 0, 0, 0);
      __builtin_amdgcn_s_setprio(0);
    }
    __syncthreads();
  }

  // D layout: col=lane&15, row=(lane>>4)*4+reg (m89/m91)
#pragma unroll
  for (int m = 0; m < 4; ++m)
#pragma unroll
    for (int n = 0; n < 4; ++n) {
      int gcol = bcol + wc + n * 16 + r;
      float bv = bias[gcol];
#pragma unroll
      for (int rr = 0; rr < 4; ++rr) {
        int grow = brow + wr + m * 16 + g * 4 + rr;
        float val = (acc[m][n][rr] + bv) * scale;
        if (OUT_MODE == 0) {
          ((float*)Outp)[grow * D + gcol] = val;
        } else if (OUT_MODE == 1) {
          ((unsigned short*)Outp)[grow * D + gcol] = f2bf(val);
        } else {
          int s = grow >> 2, bb = grow & 3;
          int hh = gcol >> 6, nh = gcol & 63;
          ((unsigned short*)Outp)[(((size_t)bb * H + hh) * NH + nh) * SL + s] = f2bf(val);
        }
      }
    }
}

__global__ __launch_bounds__(256) void qkv_gemm(
    const float* __restrict__ x0, const float* __restrict__ x1, const float* __restrict__ x2,
    const float* __restrict__ w0, const float* __restrict__ w1, const float* __restrict__ w2,
    const float* __restrict__ b0, const float* __restrict__ b1, const float* __restrict__ b2,
    unsigned short* __restrict__ outbase) {
  int z = blockIdx.z;
  const float* X = z == 0 ? x0 : (z == 1 ? x1 : x2);
  const float* W = z == 0 ? w0 : (z == 1 ? w1 : w2);
  const float* B = z == 0 ? b0 : (z == 1 ? b1 : b2);
  unsigned short* O = outbase + (size_t)z * M_ROWS * D;
  float scale = (z == 0) ? SCALE * LOG2E : 1.0f;  // fold softmax scale+log2e into Q
  if (z == 2)
    gemm_body<false, 2>(X, W, B, O, scale);
  else
    gemm_body<false, 1>(X, W, B, O, scale);
}

__global__ __launch_bounds__(256) void gemm_oproj(
    const unsigned short* __restrict__ A, const float* __restrict__ W,
    const float* __restrict__ B, float* __restrict__ Outp) {
  gemm_body<true, 0>(A, W, B, Outp, 1.0f);
}

// ---------------------------------------------------------------------------
// Flash attention, swapped-QK^T form: S^T = mfma(K, Q) puts a full key-slice
// per lane for q = lane&15 -> in-lane softmax reduce + 2 shuffles. No K/V LDS
// staging (direct L2 fragment reads; V pre-transposed by V-GEMM), no barriers;
// 1 wave per block, 32 q-rows per wave, KV tiles of 64. kf double-buffered.
// Grid: 2048 blocks, bid%8 = XCD group holding 4 (b,h) pairs (L2 locality),
// qt descending within each group.
// ---------------------------------------------------------------------------
__global__ __launch_bounds__(64) void flash_attn(
    const unsigned short* __restrict__ Q, const unsigned short* __restrict__ K,
    const unsigned short* __restrict__ Vt, unsigned short* __restrict__ O) {
  __shared__ __align__(16) unsigned short p_lds[32 * 64];

  const int bid = blockIdx.x;
  const int grp = bid & 7;                // XCD via %8 dispatch heuristic
  const int idx = bid >> 3;               // 0..255
  const int bh = grp * 4 + (idx & 3);     // 4 (b,h) pairs per XCD
  const int b = bh >> 3, h = bh & 7;
  const int qt = 63 - (idx >> 2);         // longest blocks first
  const int lane = threadIdx.x;
  const int r = lane & 15, g = lane >> 4;
  const int qw = qt * 32;
  const int kt_last = (qw + 31) >> 6;
  const int swz = (r & 7) << 3;

  const unsigned short* Qb = Q + (size_t)b * D + h * NH;
  const unsigned short* Kb = K + (size_t)b * D + h * NH;
  const unsigned short* Vb = Vt + ((size_t)(b * H + h) * NH) * SL;

  // Q fragments (B-operand): lane holds Q[q = qw+qs*16+r][nh = kk*32+g*8 ..+7]
  short8 qf[2][2];
#pragma unroll
  for (int qs = 0; qs < 2; ++qs)
#pragma unroll
    for (int kk = 0; kk < 2; ++kk)
      qf[qs][kk] = *reinterpret_cast<const short8*>(
          &Qb[(size_t)(qw + qs * 16 + r) * (BS * D) + kk * 32 + g * 8]);

  f32x4 o_acc[2][4];
#pragma unroll
  for (int qs = 0; qs < 2; ++qs)
#pragma unroll
    for (int n = 0; n < 4; ++n) o_acc[qs][n] = f32x4{0.f, 0.f, 0.f, 0.f};
  float m_run[2] = {-1e30f, -1e30f}, l_run[2] = {0.f, 0.f};

  auto load_kf = [&](short8(&kf)[2][4], int kt) {
#pragma unroll
    for (int kk = 0; kk < 2; ++kk)
#pragma unroll
      for (int n = 0; n < 4; ++n)
        kf[kk][n] = *reinterpret_cast<const short8*>(
            &Kb[(size_t)(kt * 64 + n * 16 + r) * (BS * D) + kk * 32 + g * 8]);
  };

  auto tile = [&](short8(&kf)[2][4], short8(&kfn)[2][4], int kt) {
    // V^T fragments issued first; consumed ~300+ cycles later at PV
    short8 vt[2][4];
#pragma unroll
    for (int kk = 0; kk < 2; ++kk)
#pragma unroll
      for (int n = 0; n < 4; ++n)
        vt[kk][n] = *reinterpret_cast<const short8*>(
            &Vb[(size_t)(n * 16 + r) * SL + kt * 64 + kk * 32 + g * 8]);

    // S^T = K Q : lane (r,g) holds S[q=qw+qs*16+r][key=kt*64+n*16+g*4+rr]
    f32x4 s[2][4];
#pragma unroll
    for (int qs = 0; qs < 2; ++qs)
#pragma unroll
      for (int n = 0; n < 4; ++n) s[qs][n] = f32x4{0.f, 0.f, 0.f, 0.f};
#pragma unroll
    for (int kk = 0; kk < 2; ++kk) {
      __builtin_amdgcn_s_setprio(1);
#pragma unroll
      for (int qs = 0; qs < 2; ++qs)
#pragma unroll
        for (int n = 0; n < 4; ++n)
          s[qs][n] = __builtin_amdgcn_mfma_f32_16x16x32_bf16(kf[kk][n], qf[qs][kk], s[qs][n], 0, 0, 0);
      __builtin_amdgcn_s_setprio(0);
    }

    // prefetch next K tile (hides under softmax+PV)
    if (kt + 1 <= kt_last) load_kf(kfn, kt + 1);

    // causal mask: only the diagonal tile needs it
    if (kt == kt_last) {
#pragma unroll
      for (int qs = 0; qs < 2; ++qs) {
        int qrow = qw + qs * 16 + r;
#pragma unroll
        for (int n = 0; n < 4; ++n)
#pragma unroll
          for (int rr = 0; rr < 4; ++rr)
            if (kt * 64 + n * 16 + g * 4 + rr > qrow) s[qs][n][rr] = -1e30f;
      }
    }

    // online softmax (exp2 domain; Q pre-scaled by SCALE*log2e), defer-max
#pragma unroll
    for (int qs = 0; qs < 2; ++qs) {
      float mx = s[qs][0][0];
#pragma unroll
      for (int n = 0; n < 4; ++n)
#pragma unroll
        for (int rr = 0; rr < 4; ++rr)
          if (n | rr) mx = fmaxf(mx, s[qs][n][rr]);
      mx = fmaxf(mx, __shfl_xor(mx, 16));
      mx = fmaxf(mx, __shfl_xor(mx, 32));
      bool need = __any(mx > m_run[qs] + 8.f);
      float mold = m_run[qs];
      float mnew = need ? fmaxf(mold, mx) : mold;
      float ps = 0.f;
#pragma unroll
      for (int n = 0; n < 4; ++n)
#pragma unroll
        for (int rr = 0; rr < 4; ++rr) {
          float p = fast_exp2(s[qs][n][rr] - mnew);
          s[qs][n][rr] = p;
          ps += p;
        }
      ps += __shfl_xor(ps, 16);
      ps += __shfl_xor(ps, 32);
      if (need) {
        float sf = fast_exp2(mold - mnew);
        m_run[qs] = mnew;
        l_run[qs] = l_run[qs] * sf + ps;
#pragma unroll
        for (int n = 0; n < 4; ++n) o_acc[qs][n] *= sf;
      } else {
        l_run[qs] += ps;
      }
    }

    // P^T -> per-wave LDS (packed b64, XOR-swizzled), back as B-fragments
#pragma unroll
    for (int qs = 0; qs < 2; ++qs)
#pragma unroll
      for (int n = 0; n < 4; ++n) {
        uint2v pk;
        pk.x = cvt_pk_bf16(s[qs][n][0], s[qs][n][1]);
        pk.y = cvt_pk_bf16(s[qs][n][2], s[qs][n][3]);
        *reinterpret_cast<uint2v*>(
            &p_lds[(qs * 16 + r) * 64 + ((n * 16 + g * 4) ^ swz)]) = pk;
      }
    asm volatile("s_waitcnt lgkmcnt(0)" ::: "memory");
    __builtin_amdgcn_sched_barrier(0);

#pragma unroll
    for (int kk = 0; kk < 2; ++kk) {
      short8 pf[2];
#pragma unroll
      for (int qs = 0; qs < 2; ++qs)
        pf[qs] = *reinterpret_cast<const short8*>(
            &p_lds[(qs * 16 + r) * 64 + ((kk * 32 + g * 8) ^ swz)]);
      __builtin_amdgcn_s_setprio(1);
#pragma unroll
      for (int qs = 0; qs < 2; ++qs)
#pragma unroll
        for (int n = 0; n < 4; ++n)
          o_acc[qs][n] = __builtin_amdgcn_mfma_f32_16x16x32_bf16(vt[kk][n], pf[qs], o_acc[qs][n], 0, 0, 0);
      __builtin_amdgcn_s_setprio(0);
    }
  };

  short8 kfA[2][4], kfB[2][4];
  load_kf(kfA, 0);
  int kt = 0;
  for (; kt + 1 <= kt_last; kt += 2) {
    tile(kfA, kfB, kt);
    tile(kfB, kfA, kt + 1);
  }
  if (kt == kt_last) tile(kfA, kfB, kt);

  // epilogue: normalize, transpose O^T->O via p_lds, b128 global stores
#pragma unroll
  for (int qs = 0; qs < 2; ++qs) {
    float inv = 1.0f / l_run[qs];
#pragma unroll
    for (int n = 0; n < 4; ++n) {
      uint2v pk;
      pk.x = cvt_pk_bf16(o_acc[qs][n][0] * inv, o_acc[qs][n][1] * inv);
      pk.y = cvt_pk_bf16(o_acc[qs][n][2] * inv, o_acc[qs][n][3] * inv);
      *reinterpret_cast<uint2v*>(
          &p_lds[(qs * 16 + r) * 64 + ((n * 16 + g * 4) ^ swz)]) = pk;
    }
  }
  asm volatile("s_waitcnt lgkmcnt(0)" ::: "memory");
  __builtin_amdgcn_sched_barrier(0);
  {
    const int row = lane >> 1, half = lane & 1;
    unsigned short* Ob = O + ((size_t)(qw + row) * BS + b) * D + h * NH;
#pragma unroll
    for (int i = 0; i < 4; ++i) {
      int col = (half * 4 + i) * 8;
      short8 v = *reinterpret_cast<const short8*>(&p_lds[row * 64 + col]);
      *reinterpret_cast<short8*>(&Ob[col ^ ((row & 7) << 3)]) = v;
    }
  }
}

// ---------------------------------------------------------------------------
extern "C" void kernel_launch(void* const* d_in, const int* in_sizes, int n_in,
                              void* d_out, int out_size, void* d_ws, size_t ws_size,
                              hipStream_t stream) {
  const float* x  = (const float*)d_in[0];
  const float* kx = (const float*)d_in[1];
  const float* vx = (const float*)d_in[2];
  const float* Wq = (const float*)d_in[3];
  const float* bq = (const float*)d_in[4];
  const float* Wk = (const float*)d_in[5];
  const float* bk = (const float*)d_in[6];
  const float* Wv = (const float*)d_in[7];
  const float* bv = (const float*)d_in[8];
  const float* Wo = (const float*)d_in[9];
  const float* bo = (const float*)d_in[10];

  // workspace (bf16): q | k | v^T | attn_out, 8 MB each
  unsigned short* ws = (unsigned short*)d_ws;
  unsigned short* qb = ws;
  unsigned short* kb = ws + (size_t)M_ROWS * D;
  unsigned short* vtb = ws + (size_t)M_ROWS * D * 2;
  unsigned short* ab = ws + (size_t)M_ROWS * D * 3;

  qkv_gemm<<<dim3(64, 4, 3), dim3(256), 0, stream>>>(x, kx, vx, Wq, Wk, Wv, bq, bk, bv, ws);
  flash_attn<<<dim3(2048), dim3(64), 0, stream>>>(qb, kb, vtb, ab);
  gemm_oproj<<<dim3(64, 4, 1), dim3(256), 0, stream>>>(ab, Wo, bo, (float*)d_out);
}

// Round 5
// 125.206 us; speedup vs baseline: 2.1309x; 1.3181x over previous
//
#include <hip/hip_runtime.h>

typedef __attribute__((ext_vector_type(8))) short short8;
typedef __attribute__((ext_vector_type(4))) short short4v;
typedef __attribute__((ext_vector_type(4))) float f32x4;
typedef __attribute__((ext_vector_type(2))) unsigned int uint2v;

constexpr int SL = 2048, BS = 4, D = 512, H = 8, NH = 64;
constexpr int M_ROWS = SL * BS;   // 8192
constexpr float SCALE = 0.125f;   // 1/sqrt(64)
constexpr float LOG2E = 1.44269504088896340736f;

__device__ __forceinline__ unsigned short f2bf(float f) {
  union { float f; unsigned u; } v; v.f = f;
  unsigned r = v.u + 0x7FFFu + ((v.u >> 16) & 1u);
  return (unsigned short)(r >> 16);
}

__device__ __forceinline__ unsigned cvt_pk_bf16(float a, float b) {
  unsigned r;
  asm("v_cvt_pk_bf16_f32 %0, %1, %2" : "=v"(r) : "v"(a), "v"(b));
  return r;
}

__device__ __forceinline__ float fast_exp2(float x) {
  float r;
  asm("v_exp_f32 %0, %1" : "=v"(r) : "v"(x));
  return r;
}

// async global->LDS, 16B per lane; LDS dest = wave-uniform base + lane*16
__device__ __forceinline__ void gl16(const void* g, void* l) {
  __builtin_amdgcn_global_load_lds(
      (const __attribute__((address_space(1))) unsigned int*)g,
      (__attribute__((address_space(3))) unsigned int*)l, 16, 0, 0);
}

// ---------------------------------------------------------------------------
// prep: W[512][512] f32 row-major -> W^T[n][k] bf16, LDS-tiled 64x64.
// Grid 256 blocks: wi = bx>>6 selects W, tile = bx&63.
// ---------------------------------------------------------------------------
__global__ __launch_bounds__(256) void prep_wt(
    const float* __restrict__ w0, const float* __restrict__ w1,
    const float* __restrict__ w2, const float* __restrict__ w3,
    unsigned short* __restrict__ wtb) {
  __shared__ float tl[64][65];
  const int tid = threadIdx.x;
  const int wi = blockIdx.x >> 6, t6 = blockIdx.x & 63;
  const int k0 = (t6 >> 3) * 64, n0 = (t6 & 7) * 64;
  const float* W = wi == 0 ? w0 : (wi == 1 ? w1 : (wi == 2 ? w2 : w3));
  unsigned short* WT = wtb + (size_t)wi * D * D;

#pragma unroll
  for (int i = 0; i < 4; ++i) {
    int k = (tid >> 4) + i * 16, n4 = (tid & 15) * 4;
    f32x4 v = *reinterpret_cast<const f32x4*>(&W[(size_t)(k0 + k) * D + n0 + n4]);
#pragma unroll
    for (int j = 0; j < 4; ++j) tl[n4 + j][k] = v[j];
  }
  __syncthreads();
  // 64 n-rows x 8 k8-groups = 512 short8 stores; 256 threads -> 2 iters
#pragma unroll
  for (int i = 0; i < 2; ++i) {
    int n = (tid >> 3) + i * 32, k8 = (tid & 7) * 8;
    union { unsigned u[4]; short8 s; } pk;
#pragma unroll
    for (int j = 0; j < 4; ++j)
      pk.u[j] = cvt_pk_bf16(tl[n][k8 + 2 * j], tl[n][k8 + 2 * j + 1]);
    *reinterpret_cast<short8*>(&WT[(size_t)(n0 + n) * D + k0 + k8]) = pk.s;
  }
}

// ---------------------------------------------------------------------------
// GEMM (m97 structure): C[128x128 tile] = A[M x 512] @ W^T[n][k] + bias.
// BK=64, 4 waves, linear [128][64] LDS, global_load_lds dwordx4 staging.
// A_BF16: A staged via gload_lds; else f32 reg-staged with cvt_pk + b128 write.
// OUT_MODE: 0 = f32 row-major, 1 = bf16 row-major, 2 = bf16 V^T [b][h][nh][s].
// ---------------------------------------------------------------------------
template <bool A_BF16, int OUT_MODE>
__device__ __forceinline__ void gemm_bt_body(const void* __restrict__ Ap,
                                             const unsigned short* __restrict__ BT,
                                             const float* __restrict__ bias,
                                             void* __restrict__ Outp, float scale) {
  __shared__ __align__(16) unsigned short a_lds[128 * 64];
  __shared__ __align__(16) unsigned short b_lds[128 * 64];

  const int tid = threadIdx.x;
  const int brow = blockIdx.x * 128;
  const int bcol = blockIdx.y * 128;
  const int lane = tid & 63;
  const int wid = tid >> 6;
  const int wr = (wid >> 1) * 64;
  const int wc = (wid & 1) * 64;
  const int r = lane & 15;
  const int g = lane >> 4;

  f32x4 acc[4][4];
#pragma unroll
  for (int m = 0; m < 4; ++m)
#pragma unroll
    for (int n = 0; n < 4; ++n) acc[m][n] = f32x4{0.f, 0.f, 0.f, 0.f};

  for (int kt = 0; kt < D; kt += 64) {
    // ---- stage B^T tile [128 n][64 k] via gload_lds ----
#pragma unroll
    for (int j = 0; j < 4; ++j) {
      int chunk = j * 256 + tid;
      int row = chunk >> 3, c8 = (chunk & 7) * 8;
      gl16(&BT[(size_t)(bcol + row) * D + kt + c8], &b_lds[chunk * 8]);
    }
    // ---- stage A tile [128 row][64 k] ----
    if (A_BF16) {
      const unsigned short* A = (const unsigned short*)Ap;
#pragma unroll
      for (int j = 0; j < 4; ++j) {
        int chunk = j * 256 + tid;
        int row = chunk >> 3, c8 = (chunk & 7) * 8;
        gl16(&A[(size_t)(brow + row) * D + kt + c8], &a_lds[chunk * 8]);
      }
    } else {
      const float* A = (const float*)Ap;
#pragma unroll
      for (int j = 0; j < 4; ++j) {
        int chunk = j * 256 + tid;
        int row = chunk >> 3, c8 = (chunk & 7) * 8;
        const float* ap = &A[(size_t)(brow + row) * D + kt + c8];
        f32x4 v0 = *reinterpret_cast<const f32x4*>(ap);
        f32x4 v1 = *reinterpret_cast<const f32x4*>(ap + 4);
        union { unsigned u[4]; short8 s; } pk;
        pk.u[0] = cvt_pk_bf16(v0[0], v0[1]);
        pk.u[1] = cvt_pk_bf16(v0[2], v0[3]);
        pk.u[2] = cvt_pk_bf16(v1[0], v1[1]);
        pk.u[3] = cvt_pk_bf16(v1[2], v1[3]);
        *reinterpret_cast<short8*>(&a_lds[chunk * 8]) = pk.s;
      }
    }
    __syncthreads();

#pragma unroll
    for (int kk = 0; kk < 64; kk += 32) {
      short8 af[4], bfr[4];
#pragma unroll
      for (int m = 0; m < 4; ++m)
        af[m] = *reinterpret_cast<const short8*>(&a_lds[(wr + m * 16 + r) * 64 + kk + g * 8]);
#pragma unroll
      for (int n = 0; n < 4; ++n)
        bfr[n] = *reinterpret_cast<const short8*>(&b_lds[(wc + n * 16 + r) * 64 + kk + g * 8]);
      __builtin_amdgcn_s_setprio(1);
#pragma unroll
      for (int m = 0; m < 4; ++m)
#pragma unroll
        for (int n = 0; n < 4; ++n)
          acc[m][n] = __builtin_amdgcn_mfma_f32_16x16x32_bf16(af[m], bfr[n], acc[m][n], 0, 0, 0);
      __builtin_amdgcn_s_setprio(0);
    }
    __syncthreads();
  }

  // D layout: col=lane&15, row=(lane>>4)*4+reg (m89/m91)
#pragma unroll
  for (int m = 0; m < 4; ++m)
#pragma unroll
    for (int n = 0; n < 4; ++n) {
      int gcol = bcol + wc + n * 16 + r;
      float bv = bias[gcol];
#pragma unroll
      for (int rr = 0; rr < 4; ++rr) {
        int grow = brow + wr + m * 16 + g * 4 + rr;
        float val = (acc[m][n][rr] + bv) * scale;
        if (OUT_MODE == 0) {
          ((float*)Outp)[(size_t)grow * D + gcol] = val;
        } else if (OUT_MODE == 1) {
          ((unsigned short*)Outp)[(size_t)grow * D + gcol] = f2bf(val);
        } else {
          int s = grow >> 2, bb = grow & 3;
          int hh = gcol >> 6, nh = gcol & 63;
          ((unsigned short*)Outp)[(((size_t)bb * H + hh) * NH + nh) * SL + s] = f2bf(val);
        }
      }
    }
}

__global__ __launch_bounds__(256) void qkv_gemm(
    const float* __restrict__ x0, const float* __restrict__ x1, const float* __restrict__ x2,
    const unsigned short* __restrict__ wtb,
    const float* __restrict__ b0, const float* __restrict__ b1, const float* __restrict__ b2,
    unsigned short* __restrict__ q_out, unsigned short* __restrict__ k_out,
    unsigned short* __restrict__ vt_out) {
  int z = blockIdx.z;
  const float* X = z == 0 ? x0 : (z == 1 ? x1 : x2);
  const unsigned short* WT = wtb + (size_t)z * D * D;
  const float* B = z == 0 ? b0 : (z == 1 ? b1 : b2);
  float scale = (z == 0) ? SCALE * LOG2E : 1.0f;  // fold softmax scale+log2e into Q
  if (z == 2)
    gemm_bt_body<false, 2>(X, WT, B, vt_out, scale);
  else
    gemm_bt_body<false, 1>(X, WT, B, z == 0 ? q_out : k_out, scale);
}

__global__ __launch_bounds__(256) void gemm_oproj(
    const unsigned short* __restrict__ A, const unsigned short* __restrict__ WT,
    const float* __restrict__ B, float* __restrict__ Outp) {
  gemm_bt_body<true, 0>(A, WT, B, Outp, 1.0f);
}

// ---------------------------------------------------------------------------
// Flash attention, swapped-QK^T form (round-2 structure). O is written to the
// SAME buffer as Q: each block reads only its own 32 q-rows (into registers,
// prologue) and writes only those rows/columns at epilogue -> no cross-block
// hazard.
// ---------------------------------------------------------------------------
__global__ __launch_bounds__(64) void flash_attn(
    const unsigned short* __restrict__ Q, const unsigned short* __restrict__ K,
    const unsigned short* __restrict__ Vt, unsigned short* __restrict__ O) {
  __shared__ __align__(16) unsigned short p_lds[32 * 64];

  const int bid = blockIdx.x;
  const int grp = bid & 7;                // XCD via %8 dispatch heuristic
  const int idx = bid >> 3;               // 0..255
  const int bh = grp * 4 + (idx & 3);     // 4 (b,h) pairs per XCD
  const int b = bh >> 3, h = bh & 7;
  const int qt = 63 - (idx >> 2);         // longest blocks first
  const int lane = threadIdx.x;
  const int r = lane & 15, g = lane >> 4;
  const int qw = qt * 32;
  const int kt_last = (qw + 31) >> 6;
  const int swz = (r & 7) << 3;

  const unsigned short* Qb = Q + (size_t)b * D + h * NH;
  const unsigned short* Kb = K + (size_t)b * D + h * NH;
  const unsigned short* Vb = Vt + ((size_t)(b * H + h) * NH) * SL;

  short8 qf[2][2];
#pragma unroll
  for (int qs = 0; qs < 2; ++qs)
#pragma unroll
    for (int kk = 0; kk < 2; ++kk)
      qf[qs][kk] = *reinterpret_cast<const short8*>(
          &Qb[(size_t)(qw + qs * 16 + r) * (BS * D) + kk * 32 + g * 8]);

  f32x4 o_acc[2][4];
#pragma unroll
  for (int qs = 0; qs < 2; ++qs)
#pragma unroll
    for (int n = 0; n < 4; ++n) o_acc[qs][n] = f32x4{0.f, 0.f, 0.f, 0.f};
  float m_run[2] = {-1e30f, -1e30f}, l_run[2] = {0.f, 0.f};

  auto load_kf = [&](short8(&kf)[2][4], int kt) {
#pragma unroll
    for (int kk = 0; kk < 2; ++kk)
#pragma unroll
      for (int n = 0; n < 4; ++n)
        kf[kk][n] = *reinterpret_cast<const short8*>(
            &Kb[(size_t)(kt * 64 + n * 16 + r) * (BS * D) + kk * 32 + g * 8]);
  };

  auto tile = [&](short8(&kf)[2][4], short8(&kfn)[2][4], int kt) {
    short8 vt[2][4];
#pragma unroll
    for (int kk = 0; kk < 2; ++kk)
#pragma unroll
      for (int n = 0; n < 4; ++n)
        vt[kk][n] = *reinterpret_cast<const short8*>(
            &Vb[(size_t)(n * 16 + r) * SL + kt * 64 + kk * 32 + g * 8]);

    f32x4 s[2][4];
#pragma unroll
    for (int qs = 0; qs < 2; ++qs)
#pragma unroll
      for (int n = 0; n < 4; ++n) s[qs][n] = f32x4{0.f, 0.f, 0.f, 0.f};
#pragma unroll
    for (int kk = 0; kk < 2; ++kk) {
      __builtin_amdgcn_s_setprio(1);
#pragma unroll
      for (int qs = 0; qs < 2; ++qs)
#pragma unroll
        for (int n = 0; n < 4; ++n)
          s[qs][n] = __builtin_amdgcn_mfma_f32_16x16x32_bf16(kf[kk][n], qf[qs][kk], s[qs][n], 0, 0, 0);
      __builtin_amdgcn_s_setprio(0);
    }

    if (kt + 1 <= kt_last) load_kf(kfn, kt + 1);

    if (kt == kt_last) {
#pragma unroll
      for (int qs = 0; qs < 2; ++qs) {
        int qrow = qw + qs * 16 + r;
#pragma unroll
        for (int n = 0; n < 4; ++n)
#pragma unroll
          for (int rr = 0; rr < 4; ++rr)
            if (kt * 64 + n * 16 + g * 4 + rr > qrow) s[qs][n][rr] = -1e30f;
      }
    }

#pragma unroll
    for (int qs = 0; qs < 2; ++qs) {
      float mx = s[qs][0][0];
#pragma unroll
      for (int n = 0; n < 4; ++n)
#pragma unroll
        for (int rr = 0; rr < 4; ++rr)
          if (n | rr) mx = fmaxf(mx, s[qs][n][rr]);
      mx = fmaxf(mx, __shfl_xor(mx, 16));
      mx = fmaxf(mx, __shfl_xor(mx, 32));
      bool need = __any(mx > m_run[qs] + 8.f);
      float mold = m_run[qs];
      float mnew = need ? fmaxf(mold, mx) : mold;
      float ps = 0.f;
#pragma unroll
      for (int n = 0; n < 4; ++n)
#pragma unroll
        for (int rr = 0; rr < 4; ++rr) {
          float p = fast_exp2(s[qs][n][rr] - mnew);
          s[qs][n][rr] = p;
          ps += p;
        }
      ps += __shfl_xor(ps, 16);
      ps += __shfl_xor(ps, 32);
      if (need) {
        float sf = fast_exp2(mold - mnew);
        m_run[qs] = mnew;
        l_run[qs] = l_run[qs] * sf + ps;
#pragma unroll
        for (int n = 0; n < 4; ++n) o_acc[qs][n] *= sf;
      } else {
        l_run[qs] += ps;
      }
    }

#pragma unroll
    for (int qs = 0; qs < 2; ++qs)
#pragma unroll
      for (int n = 0; n < 4; ++n) {
        uint2v pk;
        pk.x = cvt_pk_bf16(s[qs][n][0], s[qs][n][1]);
        pk.y = cvt_pk_bf16(s[qs][n][2], s[qs][n][3]);
        *reinterpret_cast<uint2v*>(
            &p_lds[(qs * 16 + r) * 64 + ((n * 16 + g * 4) ^ swz)]) = pk;
      }
    asm volatile("s_waitcnt lgkmcnt(0)" ::: "memory");
    __builtin_amdgcn_sched_barrier(0);

#pragma unroll
    for (int kk = 0; kk < 2; ++kk) {
      short8 pf[2];
#pragma unroll
      for (int qs = 0; qs < 2; ++qs)
        pf[qs] = *reinterpret_cast<const short8*>(
            &p_lds[(qs * 16 + r) * 64 + ((kk * 32 + g * 8) ^ swz)]);
      __builtin_amdgcn_s_setprio(1);
#pragma unroll
      for (int qs = 0; qs < 2; ++qs)
#pragma unroll
        for (int n = 0; n < 4; ++n)
          o_acc[qs][n] = __builtin_amdgcn_mfma_f32_16x16x32_bf16(vt[kk][n], pf[qs], o_acc[qs][n], 0, 0, 0);
      __builtin_amdgcn_s_setprio(0);
    }
  };

  short8 kfA[2][4], kfB[2][4];
  load_kf(kfA, 0);
  int kt = 0;
  for (; kt + 1 <= kt_last; kt += 2) {
    tile(kfA, kfB, kt);
    tile(kfB, kfA, kt + 1);
  }
  if (kt == kt_last) tile(kfA, kfB, kt);

#pragma unroll
  for (int qs = 0; qs < 2; ++qs) {
    float inv = 1.0f / l_run[qs];
#pragma unroll
    for (int n = 0; n < 4; ++n) {
      uint2v pk;
      pk.x = cvt_pk_bf16(o_acc[qs][n][0] * inv, o_acc[qs][n][1] * inv);
      pk.y = cvt_pk_bf16(o_acc[qs][n][2] * inv, o_acc[qs][n][3] * inv);
      *reinterpret_cast<uint2v*>(
          &p_lds[(qs * 16 + r) * 64 + ((n * 16 + g * 4) ^ swz)]) = pk;
    }
  }
  asm volatile("s_waitcnt lgkmcnt(0)" ::: "memory");
  __builtin_amdgcn_sched_barrier(0);
  {
    const int row = lane >> 1, half = lane & 1;
    unsigned short* Ob = O + ((size_t)(qw + row) * BS + b) * D + h * NH;
#pragma unroll
    for (int i = 0; i < 4; ++i) {
      int col = (half * 4 + i) * 8;
      short8 v = *reinterpret_cast<const short8*>(&p_lds[row * 64 + col]);
      *reinterpret_cast<short8*>(&Ob[col ^ ((row & 7) << 3)]) = v;
    }
  }
}

// ---------------------------------------------------------------------------
extern "C" void kernel_launch(void* const* d_in, const int* in_sizes, int n_in,
                              void* d_out, int out_size, void* d_ws, size_t ws_size,
                              hipStream_t stream) {
  const float* x  = (const float*)d_in[0];
  const float* kx = (const float*)d_in[1];
  const float* vx = (const float*)d_in[2];
  const float* Wq = (const float*)d_in[3];
  const float* bq = (const float*)d_in[4];
  const float* Wk = (const float*)d_in[5];
  const float* bk = (const float*)d_in[6];
  const float* Wv = (const float*)d_in[7];
  const float* bv = (const float*)d_in[8];
  const float* Wo = (const float*)d_in[9];
  const float* bo = (const float*)d_in[10];

  // workspace (bf16), 26 MB total (<= 32 MB proven in round 2):
  //   qb (8 MB, attn-out aliases it) | kb (8 MB) | vtb (8 MB) | wtb (2 MB)
  unsigned short* ws = (unsigned short*)d_ws;
  unsigned short* qb  = ws;                              // Q, then attn-out
  unsigned short* kb  = ws + (size_t)M_ROWS * D;
  unsigned short* vtb = ws + (size_t)M_ROWS * D * 2;
  unsigned short* wtb = ws + (size_t)M_ROWS * D * 3;     // 4x W^T, 2 MB

  prep_wt<<<dim3(256), dim3(256), 0, stream>>>(Wq, Wk, Wv, Wo, wtb);
  qkv_gemm<<<dim3(64, 4, 3), dim3(256), 0, stream>>>(x, kx, vx, wtb, bq, bk, bv,
                                                     qb, kb, vtb);
  flash_attn<<<dim3(2048), dim3(64), 0, stream>>>(qb, kb, vtb, qb);
  gemm_oproj<<<dim3(64, 4, 1), dim3(256), 0, stream>>>(qb, wtb + (size_t)3 * D * D,
                                                       bo, (float*)d_out);
}

// Round 6
// 103.460 us; speedup vs baseline: 2.5788x; 1.2102x over previous
//
#include <hip/hip_runtime.h>

typedef __attribute__((ext_vector_type(8))) short short8;
typedef __attribute__((ext_vector_type(4))) short short4v;
typedef __attribute__((ext_vector_type(4))) float f32x4;
typedef __attribute__((ext_vector_type(2))) unsigned int uint2v;

constexpr int SL = 2048, BS = 4, D = 512, H = 8, NH = 64;
constexpr int M_ROWS = SL * BS;   // 8192
constexpr float SCALE = 0.125f;   // 1/sqrt(64)
constexpr float LOG2E = 1.44269504088896340736f;

__device__ __forceinline__ unsigned short f2bf(float f) {
  union { float f; unsigned u; } v; v.f = f;
  unsigned r = v.u + 0x7FFFu + ((v.u >> 16) & 1u);
  return (unsigned short)(r >> 16);
}

__device__ __forceinline__ unsigned cvt_pk_bf16(float a, float b) {
  unsigned r;
  asm("v_cvt_pk_bf16_f32 %0, %1, %2" : "=v"(r) : "v"(a), "v"(b));
  return r;
}

__device__ __forceinline__ float fast_exp2(float x) {
  float r;
  asm("v_exp_f32 %0, %1" : "=v"(r) : "v"(x));
  return r;
}

// async global->LDS, 16B per lane; LDS dest = wave-uniform base + lane*16
__device__ __forceinline__ void gl16(const void* g, void* l) {
  __builtin_amdgcn_global_load_lds(
      (const __attribute__((address_space(1))) unsigned int*)g,
      (__attribute__((address_space(3))) unsigned int*)l, 16, 0, 0);
}

// ---------------------------------------------------------------------------
// prep: W[512][512] f32 row-major -> W^T[n][k] bf16, LDS-tiled 64x64.
// ---------------------------------------------------------------------------
__global__ __launch_bounds__(256) void prep_wt(
    const float* __restrict__ w0, const float* __restrict__ w1,
    const float* __restrict__ w2, const float* __restrict__ w3,
    unsigned short* __restrict__ wtb) {
  __shared__ float tl[64][65];
  const int tid = threadIdx.x;
  const int wi = blockIdx.x >> 6, t6 = blockIdx.x & 63;
  const int k0 = (t6 >> 3) * 64, n0 = (t6 & 7) * 64;
  const float* W = wi == 0 ? w0 : (wi == 1 ? w1 : (wi == 2 ? w2 : w3));
  unsigned short* WT = wtb + (size_t)wi * D * D;

#pragma unroll
  for (int i = 0; i < 4; ++i) {
    int k = (tid >> 4) + i * 16, n4 = (tid & 15) * 4;
    f32x4 v = *reinterpret_cast<const f32x4*>(&W[(size_t)(k0 + k) * D + n0 + n4]);
#pragma unroll
    for (int j = 0; j < 4; ++j) tl[n4 + j][k] = v[j];
  }
  __syncthreads();
#pragma unroll
  for (int i = 0; i < 2; ++i) {
    int n = (tid >> 3) + i * 32, k8 = (tid & 7) * 8;
    union { unsigned u[4]; short8 s; } pk;
#pragma unroll
    for (int j = 0; j < 4; ++j)
      pk.u[j] = cvt_pk_bf16(tl[n][k8 + 2 * j], tl[n][k8 + 2 * j + 1]);
    *reinterpret_cast<short8*>(&WT[(size_t)(n0 + n) * D + k0 + k8]) = pk.s;
  }
}

// ---------------------------------------------------------------------------
// GEMM (m97 structure), unchanged from round 5.
// ---------------------------------------------------------------------------
template <bool A_BF16, int OUT_MODE>
__device__ __forceinline__ void gemm_bt_body(const void* __restrict__ Ap,
                                             const unsigned short* __restrict__ BT,
                                             const float* __restrict__ bias,
                                             void* __restrict__ Outp, float scale) {
  __shared__ __align__(16) unsigned short a_lds[128 * 64];
  __shared__ __align__(16) unsigned short b_lds[128 * 64];

  const int tid = threadIdx.x;
  const int brow = blockIdx.x * 128;
  const int bcol = blockIdx.y * 128;
  const int lane = tid & 63;
  const int wid = tid >> 6;
  const int wr = (wid >> 1) * 64;
  const int wc = (wid & 1) * 64;
  const int r = lane & 15;
  const int g = lane >> 4;

  f32x4 acc[4][4];
#pragma unroll
  for (int m = 0; m < 4; ++m)
#pragma unroll
    for (int n = 0; n < 4; ++n) acc[m][n] = f32x4{0.f, 0.f, 0.f, 0.f};

  for (int kt = 0; kt < D; kt += 64) {
#pragma unroll
    for (int j = 0; j < 4; ++j) {
      int chunk = j * 256 + tid;
      int row = chunk >> 3, c8 = (chunk & 7) * 8;
      gl16(&BT[(size_t)(bcol + row) * D + kt + c8], &b_lds[chunk * 8]);
    }
    if (A_BF16) {
      const unsigned short* A = (const unsigned short*)Ap;
#pragma unroll
      for (int j = 0; j < 4; ++j) {
        int chunk = j * 256 + tid;
        int row = chunk >> 3, c8 = (chunk & 7) * 8;
        gl16(&A[(size_t)(brow + row) * D + kt + c8], &a_lds[chunk * 8]);
      }
    } else {
      const float* A = (const float*)Ap;
#pragma unroll
      for (int j = 0; j < 4; ++j) {
        int chunk = j * 256 + tid;
        int row = chunk >> 3, c8 = (chunk & 7) * 8;
        const float* ap = &A[(size_t)(brow + row) * D + kt + c8];
        f32x4 v0 = *reinterpret_cast<const f32x4*>(ap);
        f32x4 v1 = *reinterpret_cast<const f32x4*>(ap + 4);
        union { unsigned u[4]; short8 s; } pk;
        pk.u[0] = cvt_pk_bf16(v0[0], v0[1]);
        pk.u[1] = cvt_pk_bf16(v0[2], v0[3]);
        pk.u[2] = cvt_pk_bf16(v1[0], v1[1]);
        pk.u[3] = cvt_pk_bf16(v1[2], v1[3]);
        *reinterpret_cast<short8*>(&a_lds[chunk * 8]) = pk.s;
      }
    }
    __syncthreads();

#pragma unroll
    for (int kk = 0; kk < 64; kk += 32) {
      short8 af[4], bfr[4];
#pragma unroll
      for (int m = 0; m < 4; ++m)
        af[m] = *reinterpret_cast<const short8*>(&a_lds[(wr + m * 16 + r) * 64 + kk + g * 8]);
#pragma unroll
      for (int n = 0; n < 4; ++n)
        bfr[n] = *reinterpret_cast<const short8*>(&b_lds[(wc + n * 16 + r) * 64 + kk + g * 8]);
      __builtin_amdgcn_s_setprio(1);
#pragma unroll
      for (int m = 0; m < 4; ++m)
#pragma unroll
        for (int n = 0; n < 4; ++n)
          acc[m][n] = __builtin_amdgcn_mfma_f32_16x16x32_bf16(af[m], bfr[n], acc[m][n], 0, 0, 0);
      __builtin_amdgcn_s_setprio(0);
    }
    __syncthreads();
  }

#pragma unroll
  for (int m = 0; m < 4; ++m)
#pragma unroll
    for (int n = 0; n < 4; ++n) {
      int gcol = bcol + wc + n * 16 + r;
      float bv = bias[gcol];
#pragma unroll
      for (int rr = 0; rr < 4; ++rr) {
        int grow = brow + wr + m * 16 + g * 4 + rr;
        float val = (acc[m][n][rr] + bv) * scale;
        if (OUT_MODE == 0) {
          ((float*)Outp)[(size_t)grow * D + gcol] = val;
        } else if (OUT_MODE == 1) {
          ((unsigned short*)Outp)[(size_t)grow * D + gcol] = f2bf(val);
        } else {
          int s = grow >> 2, bb = grow & 3;
          int hh = gcol >> 6, nh = gcol & 63;
          ((unsigned short*)Outp)[(((size_t)bb * H + hh) * NH + nh) * SL + s] = f2bf(val);
        }
      }
    }
}

__global__ __launch_bounds__(256) void qkv_gemm(
    const float* __restrict__ x0, const float* __restrict__ x1, const float* __restrict__ x2,
    const unsigned short* __restrict__ wtb,
    const float* __restrict__ b0, const float* __restrict__ b1, const float* __restrict__ b2,
    unsigned short* __restrict__ q_out, unsigned short* __restrict__ k_out,
    unsigned short* __restrict__ vt_out) {
  int z = blockIdx.z;
  const float* X = z == 0 ? x0 : (z == 1 ? x1 : x2);
  const unsigned short* WT = wtb + (size_t)z * D * D;
  const float* B = z == 0 ? b0 : (z == 1 ? b1 : b2);
  float scale = (z == 0) ? SCALE * LOG2E : 1.0f;
  if (z == 2)
    gemm_bt_body<false, 2>(X, WT, B, vt_out, scale);
  else
    gemm_bt_body<false, 1>(X, WT, B, z == 0 ? q_out : k_out, scale);
}

__global__ __launch_bounds__(256) void gemm_oproj(
    const unsigned short* __restrict__ A, const unsigned short* __restrict__ WT,
    const float* __restrict__ B, float* __restrict__ Outp) {
  gemm_bt_body<true, 0>(A, WT, B, Outp, 1.0f);
}

// ---------------------------------------------------------------------------
// Flash attention v3: 4-wave blocks, LDS-shared K/V (pre-swizzled-source
// global_load_lds, double-buffered), balanced q-tile pairs (t, 31-t) so every
// block runs exactly 33 phases. Per wave: 16 q-rows, swapped-QK^T in-lane
// softmax. One raw barrier per phase; stage(next) issued right after it so
// loads hide under compute. O aliases Q (block touches only its own rows).
// ---------------------------------------------------------------------------
__global__ __launch_bounds__(256, 2) void flash_attn(
    const unsigned short* __restrict__ Q, const unsigned short* __restrict__ K,
    const unsigned short* __restrict__ Vt, unsigned short* __restrict__ O) {
  __shared__ __align__(16) unsigned short k_lds[2][64 * 64];
  __shared__ __align__(16) unsigned short v_lds[2][64 * 64];
  __shared__ __align__(16) unsigned short p_lds[4][16 * 64];

  const int bid = blockIdx.x;
  const int grp = bid & 7;              // XCD group: 4 (b,h) pairs each
  const int i = bid >> 3;               // 0..63
  const int bh = grp * 4 + (i & 3);
  const int b = bh >> 3, h = bh & 7;
  const int t = i >> 2;                 // 0..15 -> q-tile pair (t, 31-t)
  const int qtA = t, qtB = 31 - t;      // phases: (qtA+1)+(qtB+1) = 33
  const int q0A = qtA * 64, q0B = qtB * 64;

  const int tid = threadIdx.x;
  const int w = tid >> 6, lane = tid & 63;
  const int r = lane & 15, g = lane >> 4;
  const int swz = (r & 7) << 3;

  const unsigned short* Qb = Q + (size_t)b * D + h * NH;
  const unsigned short* Kb = K + (size_t)b * D + h * NH;
  const unsigned short* Vb = Vt + ((size_t)(b * H + h) * NH) * SL;
  unsigned short* Ob = O + (size_t)b * D + h * NH;
  unsigned short* pw = &p_lds[w][0];

  // stage tile kt into buffer bsel: linear LDS dest, swizzled global source
  auto STAGE = [&](int kt, int bsel) {
    unsigned short* kl = &k_lds[bsel][0];
    unsigned short* vl = &v_lds[bsel][0];
#pragma unroll
    for (int j = 0; j < 2; ++j) {
      int c = j * 256 + tid;
      int row = c >> 3, c8 = (c & 7) ^ (row & 7);
      gl16(&Kb[(size_t)(kt * 64 + row) * (BS * D) + c8 * 8], &kl[c * 8]);
      gl16(&Vb[(size_t)row * SL + kt * 64 + c8 * 8], &vl[c * 8]);
    }
  };

  STAGE(0, 0);

  // Q fragments for both q-tiles (16 rows/wave)
  short8 qfA[2], qfB[2];
#pragma unroll
  for (int kk = 0; kk < 2; ++kk) {
    qfA[kk] = *reinterpret_cast<const short8*>(
        &Qb[(size_t)(q0A + w * 16 + r) * (BS * D) + kk * 32 + g * 8]);
    qfB[kk] = *reinterpret_cast<const short8*>(
        &Qb[(size_t)(q0B + w * 16 + r) * (BS * D) + kk * 32 + g * 8]);
  }

  f32x4 oa[4];
  float mr, lr;
  auto reset_acc = [&]() {
#pragma unroll
    for (int n = 0; n < 4; ++n) oa[n] = f32x4{0.f, 0.f, 0.f, 0.f};
    mr = -1e30f; lr = 0.f;
  };
  reset_acc();

  auto compute = [&](int q0w, int kt, bool diag, short8(&qf)[2], int bsel) {
    const unsigned short* kl = &k_lds[bsel][0];
    const unsigned short* vl = &v_lds[bsel][0];
    short8 kf[2][4], vt[2][4];
#pragma unroll
    for (int kk = 0; kk < 2; ++kk)
#pragma unroll
      for (int n = 0; n < 4; ++n)
        kf[kk][n] = *reinterpret_cast<const short8*>(
            &kl[(n * 16 + r) * 64 + (((kk * 4 + g) ^ (r & 7)) * 8)]);

    f32x4 s[4];
#pragma unroll
    for (int n = 0; n < 4; ++n) s[n] = f32x4{0.f, 0.f, 0.f, 0.f};
#pragma unroll
    for (int kk = 0; kk < 2; ++kk) {
      __builtin_amdgcn_s_setprio(1);
#pragma unroll
      for (int n = 0; n < 4; ++n)
        s[n] = __builtin_amdgcn_mfma_f32_16x16x32_bf16(kf[kk][n], qf[kk], s[n], 0, 0, 0);
      __builtin_amdgcn_s_setprio(0);
    }

    // V^T fragments: issue now, consumed after softmax
#pragma unroll
    for (int kk = 0; kk < 2; ++kk)
#pragma unroll
      for (int n = 0; n < 4; ++n)
        vt[kk][n] = *reinterpret_cast<const short8*>(
            &vl[(n * 16 + r) * 64 + (((kk * 4 + g) ^ (r & 7)) * 8)]);

    if (diag) {
      int qrow = q0w + r;
#pragma unroll
      for (int n = 0; n < 4; ++n)
#pragma unroll
        for (int rr = 0; rr < 4; ++rr)
          if (kt * 64 + n * 16 + g * 4 + rr > qrow) s[n][rr] = -1e30f;
    }

    float mx = s[0][0];
#pragma unroll
    for (int n = 0; n < 4; ++n)
#pragma unroll
      for (int rr = 0; rr < 4; ++rr)
        if (n | rr) mx = fmaxf(mx, s[n][rr]);
    mx = fmaxf(mx, __shfl_xor(mx, 16));
    mx = fmaxf(mx, __shfl_xor(mx, 32));
    bool need = __any(mx > mr + 8.f);
    float mold = mr;
    float mnew = need ? fmaxf(mold, mx) : mold;
    float ps = 0.f;
#pragma unroll
    for (int n = 0; n < 4; ++n)
#pragma unroll
      for (int rr = 0; rr < 4; ++rr) {
        float p = fast_exp2(s[n][rr] - mnew);
        s[n][rr] = p;
        ps += p;
      }
    ps += __shfl_xor(ps, 16);
    ps += __shfl_xor(ps, 32);
    if (need) {
      float sf = fast_exp2(mold - mnew);
      mr = mnew;
      lr = lr * sf + ps;
#pragma unroll
      for (int n = 0; n < 4; ++n) oa[n] *= sf;
    } else {
      lr += ps;
    }

#pragma unroll
    for (int n = 0; n < 4; ++n) {
      uint2v pk;
      pk.x = cvt_pk_bf16(s[n][0], s[n][1]);
      pk.y = cvt_pk_bf16(s[n][2], s[n][3]);
      *reinterpret_cast<uint2v*>(&pw[r * 64 + ((n * 16 + g * 4) ^ swz)]) = pk;
    }
    asm volatile("s_waitcnt lgkmcnt(0)" ::: "memory");
    __builtin_amdgcn_sched_barrier(0);

    short8 pf[2];
#pragma unroll
    for (int kk = 0; kk < 2; ++kk)
      pf[kk] = *reinterpret_cast<const short8*>(
          &pw[r * 64 + (((kk * 4 + g) ^ (r & 7)) * 8)]);
#pragma unroll
    for (int kk = 0; kk < 2; ++kk) {
      __builtin_amdgcn_s_setprio(1);
#pragma unroll
      for (int n = 0; n < 4; ++n)
        oa[n] = __builtin_amdgcn_mfma_f32_16x16x32_bf16(vt[kk][n], pf[kk], oa[n], 0, 0, 0);
      __builtin_amdgcn_s_setprio(0);
    }
  };

  auto finalize = [&](int q0) {
    float inv = 1.0f / lr;
#pragma unroll
    for (int n = 0; n < 4; ++n) {
      uint2v pk;
      pk.x = cvt_pk_bf16(oa[n][0] * inv, oa[n][1] * inv);
      pk.y = cvt_pk_bf16(oa[n][2] * inv, oa[n][3] * inv);
      *reinterpret_cast<uint2v*>(&pw[r * 64 + ((n * 16 + g * 4) ^ swz)]) = pk;
    }
    asm volatile("s_waitcnt lgkmcnt(0)" ::: "memory");
    __builtin_amdgcn_sched_barrier(0);
#pragma unroll
    for (int i2 = 0; i2 < 2; ++i2) {
      int c = i2 * 64 + lane;
      int row = c >> 3, c8 = c & 7;
      short8 v = *reinterpret_cast<const short8*>(&pw[row * 64 + c8 * 8]);
      *reinterpret_cast<short8*>(
          &Ob[(size_t)(q0 + w * 16 + row) * (BS * D) + ((c8 ^ (row & 7)) * 8)]) = v;
    }
  };

  int ph = 0;
  // ---- q-tile A ----
  for (int kt = 0; kt <= qtA; ++kt, ++ph) {
    asm volatile("s_waitcnt vmcnt(0)" ::: "memory");
    __builtin_amdgcn_s_barrier();
    __builtin_amdgcn_sched_barrier(0);
    int np = ph + 1;
    if (np < 33) STAGE(np <= qtA ? np : np - qtA - 1, np & 1);
    compute(q0A + w * 16, kt, kt == qtA, qfA, ph & 1);
  }
  finalize(q0A);
  reset_acc();
  // ---- q-tile B ----
  for (int kt = 0; kt <= qtB; ++kt, ++ph) {
    asm volatile("s_waitcnt vmcnt(0)" ::: "memory");
    __builtin_amdgcn_s_barrier();
    __builtin_amdgcn_sched_barrier(0);
    int np = ph + 1;
    if (np < 33) STAGE(np - qtA - 1, np & 1);
    compute(q0B + w * 16, kt, kt == qtB, qfB, ph & 1);
  }
  finalize(q0B);
}

// ---------------------------------------------------------------------------
extern "C" void kernel_launch(void* const* d_in, const int* in_sizes, int n_in,
                              void* d_out, int out_size, void* d_ws, size_t ws_size,
                              hipStream_t stream) {
  const float* x  = (const float*)d_in[0];
  const float* kx = (const float*)d_in[1];
  const float* vx = (const float*)d_in[2];
  const float* Wq = (const float*)d_in[3];
  const float* bq = (const float*)d_in[4];
  const float* Wk = (const float*)d_in[5];
  const float* bk = (const float*)d_in[6];
  const float* Wv = (const float*)d_in[7];
  const float* bv = (const float*)d_in[8];
  const float* Wo = (const float*)d_in[9];
  const float* bo = (const float*)d_in[10];

  // workspace (bf16), 26 MB: qb (attn-out aliases) | kb | vtb | wtb (2 MB)
  unsigned short* ws = (unsigned short*)d_ws;
  unsigned short* qb  = ws;
  unsigned short* kb  = ws + (size_t)M_ROWS * D;
  unsigned short* vtb = ws + (size_t)M_ROWS * D * 2;
  unsigned short* wtb = ws + (size_t)M_ROWS * D * 3;

  prep_wt<<<dim3(256), dim3(256), 0, stream>>>(Wq, Wk, Wv, Wo, wtb);
  qkv_gemm<<<dim3(64, 4, 3), dim3(256), 0, stream>>>(x, kx, vx, wtb, bq, bk, bv,
                                                     qb, kb, vtb);
  flash_attn<<<dim3(512), dim3(256), 0, stream>>>(qb, kb, vtb, qb);
  gemm_oproj<<<dim3(64, 4, 1), dim3(256), 0, stream>>>(qb, wtb + (size_t)3 * D * D,
                                                       bo, (float*)d_out);
}

// Round 7
// 97.121 us; speedup vs baseline: 2.7471x; 1.0653x over previous
//
#include <hip/hip_runtime.h>

typedef __attribute__((ext_vector_type(8))) short short8;
typedef __attribute__((ext_vector_type(4))) short short4v;
typedef __attribute__((ext_vector_type(4))) float f32x4;
typedef __attribute__((ext_vector_type(2))) unsigned int uint2v;

constexpr int SL = 2048, BS = 4, D = 512, H = 8, NH = 64;
constexpr int M_ROWS = SL * BS;   // 8192
constexpr float SCALE = 0.125f;   // 1/sqrt(64)
constexpr float LOG2E = 1.44269504088896340736f;

__device__ __forceinline__ unsigned short f2bf(float f) {
  union { float f; unsigned u; } v; v.f = f;
  unsigned r = v.u + 0x7FFFu + ((v.u >> 16) & 1u);
  return (unsigned short)(r >> 16);
}

__device__ __forceinline__ unsigned cvt_pk_bf16(float a, float b) {
  unsigned r;
  asm("v_cvt_pk_bf16_f32 %0, %1, %2" : "=v"(r) : "v"(a), "v"(b));
  return r;
}

__device__ __forceinline__ float fast_exp2(float x) {
  float r;
  asm("v_exp_f32 %0, %1" : "=v"(r) : "v"(x));
  return r;
}

// async global->LDS, 16B per lane; LDS dest = wave-uniform base + lane*16
__device__ __forceinline__ void gl16(const void* g, void* l) {
  __builtin_amdgcn_global_load_lds(
      (const __attribute__((address_space(1))) unsigned int*)g,
      (__attribute__((address_space(3))) unsigned int*)l, 16, 0, 0);
}

// ---------------------------------------------------------------------------
// prep: W[512][512] f32 row-major -> W^T[n][k] bf16, LDS-tiled 64x64.
// ---------------------------------------------------------------------------
__global__ __launch_bounds__(256) void prep_wt(
    const float* __restrict__ w0, const float* __restrict__ w1,
    const float* __restrict__ w2, const float* __restrict__ w3,
    unsigned short* __restrict__ wtb) {
  __shared__ float tl[64][65];
  const int tid = threadIdx.x;
  const int wi = blockIdx.x >> 6, t6 = blockIdx.x & 63;
  const int k0 = (t6 >> 3) * 64, n0 = (t6 & 7) * 64;
  const float* W = wi == 0 ? w0 : (wi == 1 ? w1 : (wi == 2 ? w2 : w3));
  unsigned short* WT = wtb + (size_t)wi * D * D;

#pragma unroll
  for (int i = 0; i < 4; ++i) {
    int k = (tid >> 4) + i * 16, n4 = (tid & 15) * 4;
    f32x4 v = *reinterpret_cast<const f32x4*>(&W[(size_t)(k0 + k) * D + n0 + n4]);
#pragma unroll
    for (int j = 0; j < 4; ++j) tl[n4 + j][k] = v[j];
  }
  __syncthreads();
#pragma unroll
  for (int i = 0; i < 2; ++i) {
    int n = (tid >> 3) + i * 32, k8 = (tid & 7) * 8;
    union { unsigned u[4]; short8 s; } pk;
#pragma unroll
    for (int j = 0; j < 4; ++j)
      pk.u[j] = cvt_pk_bf16(tl[n][k8 + 2 * j], tl[n][k8 + 2 * j + 1]);
    *reinterpret_cast<short8*>(&WT[(size_t)(n0 + n) * D + k0 + k8]) = pk.s;
  }
}

// ---------------------------------------------------------------------------
// GEMM (m97 structure). LDS tiles are OWNED BY THE CALLER: a single 32 KB
// a_lds/b_lds pair is passed in, so multiple template instantiations in one
// kernel share it (the in-template __shared__ gave 2x32 KB and halved
// residency -> round-6's 12.7% occupancy).
// ---------------------------------------------------------------------------
template <bool A_BF16, int OUT_MODE>
__device__ __forceinline__ void gemm_bt_body(const void* __restrict__ Ap,
                                             const unsigned short* __restrict__ BT,
                                             const float* __restrict__ bias,
                                             void* __restrict__ Outp, float scale,
                                             unsigned short* a_lds,
                                             unsigned short* b_lds) {
  const int tid = threadIdx.x;
  const int brow = blockIdx.x * 128;
  const int bcol = blockIdx.y * 128;
  const int lane = tid & 63;
  const int wid = tid >> 6;
  const int wr = (wid >> 1) * 64;
  const int wc = (wid & 1) * 64;
  const int r = lane & 15;
  const int g = lane >> 4;

  f32x4 acc[4][4];
#pragma unroll
  for (int m = 0; m < 4; ++m)
#pragma unroll
    for (int n = 0; n < 4; ++n) acc[m][n] = f32x4{0.f, 0.f, 0.f, 0.f};

  for (int kt = 0; kt < D; kt += 64) {
#pragma unroll
    for (int j = 0; j < 4; ++j) {
      int chunk = j * 256 + tid;
      int row = chunk >> 3, c8 = (chunk & 7) * 8;
      gl16(&BT[(size_t)(bcol + row) * D + kt + c8], &b_lds[chunk * 8]);
    }
    if (A_BF16) {
      const unsigned short* A = (const unsigned short*)Ap;
#pragma unroll
      for (int j = 0; j < 4; ++j) {
        int chunk = j * 256 + tid;
        int row = chunk >> 3, c8 = (chunk & 7) * 8;
        gl16(&A[(size_t)(brow + row) * D + kt + c8], &a_lds[chunk * 8]);
      }
    } else {
      const float* A = (const float*)Ap;
#pragma unroll
      for (int j = 0; j < 4; ++j) {
        int chunk = j * 256 + tid;
        int row = chunk >> 3, c8 = (chunk & 7) * 8;
        const float* ap = &A[(size_t)(brow + row) * D + kt + c8];
        f32x4 v0 = *reinterpret_cast<const f32x4*>(ap);
        f32x4 v1 = *reinterpret_cast<const f32x4*>(ap + 4);
        union { unsigned u[4]; short8 s; } pk;
        pk.u[0] = cvt_pk_bf16(v0[0], v0[1]);
        pk.u[1] = cvt_pk_bf16(v0[2], v0[3]);
        pk.u[2] = cvt_pk_bf16(v1[0], v1[1]);
        pk.u[3] = cvt_pk_bf16(v1[2], v1[3]);
        *reinterpret_cast<short8*>(&a_lds[chunk * 8]) = pk.s;
      }
    }
    __syncthreads();

#pragma unroll
    for (int kk = 0; kk < 64; kk += 32) {
      short8 af[4], bfr[4];
#pragma unroll
      for (int m = 0; m < 4; ++m)
        af[m] = *reinterpret_cast<const short8*>(&a_lds[(wr + m * 16 + r) * 64 + kk + g * 8]);
#pragma unroll
      for (int n = 0; n < 4; ++n)
        bfr[n] = *reinterpret_cast<const short8*>(&b_lds[(wc + n * 16 + r) * 64 + kk + g * 8]);
      __builtin_amdgcn_s_setprio(1);
#pragma unroll
      for (int m = 0; m < 4; ++m)
#pragma unroll
        for (int n = 0; n < 4; ++n)
          acc[m][n] = __builtin_amdgcn_mfma_f32_16x16x32_bf16(af[m], bfr[n], acc[m][n], 0, 0, 0);
      __builtin_amdgcn_s_setprio(0);
    }
    __syncthreads();
  }

#pragma unroll
  for (int m = 0; m < 4; ++m)
#pragma unroll
    for (int n = 0; n < 4; ++n) {
      int gcol = bcol + wc + n * 16 + r;
      float bv = bias[gcol];
#pragma unroll
      for (int rr = 0; rr < 4; ++rr) {
        int grow = brow + wr + m * 16 + g * 4 + rr;
        float val = (acc[m][n][rr] + bv) * scale;
        if (OUT_MODE == 0) {
          ((float*)Outp)[(size_t)grow * D + gcol] = val;
        } else if (OUT_MODE == 1) {
          ((unsigned short*)Outp)[(size_t)grow * D + gcol] = f2bf(val);
        } else {
          int s = grow >> 2, bb = grow & 3;
          int hh = gcol >> 6, nh = gcol & 63;
          ((unsigned short*)Outp)[(((size_t)bb * H + hh) * NH + nh) * SL + s] = f2bf(val);
        }
      }
    }
}

__global__ __launch_bounds__(256, 4) void qkv_gemm(
    const float* __restrict__ x0, const float* __restrict__ x1, const float* __restrict__ x2,
    const unsigned short* __restrict__ wtb,
    const float* __restrict__ b0, const float* __restrict__ b1, const float* __restrict__ b2,
    unsigned short* __restrict__ q_out, unsigned short* __restrict__ k_out,
    unsigned short* __restrict__ vt_out) {
  __shared__ __align__(16) unsigned short a_lds[128 * 64];
  __shared__ __align__(16) unsigned short b_lds[128 * 64];
  int z = blockIdx.z;
  const float* X = z == 0 ? x0 : (z == 1 ? x1 : x2);
  const unsigned short* WT = wtb + (size_t)z * D * D;
  const float* B = z == 0 ? b0 : (z == 1 ? b1 : b2);
  float scale = (z == 0) ? SCALE * LOG2E : 1.0f;
  if (z == 2)
    gemm_bt_body<false, 2>(X, WT, B, vt_out, scale, a_lds, b_lds);
  else
    gemm_bt_body<false, 1>(X, WT, B, z == 0 ? q_out : k_out, scale, a_lds, b_lds);
}

__global__ __launch_bounds__(256, 4) void gemm_oproj(
    const unsigned short* __restrict__ A, const unsigned short* __restrict__ WT,
    const float* __restrict__ B, float* __restrict__ Outp) {
  __shared__ __align__(16) unsigned short a_lds[128 * 64];
  __shared__ __align__(16) unsigned short b_lds[128 * 64];
  gemm_bt_body<true, 0>(A, WT, B, Outp, 1.0f, a_lds, b_lds);
}

// ---------------------------------------------------------------------------
// Flash attention v3 (unchanged from round 6): 4-wave blocks, LDS-shared K/V
// double-buffered via pre-swizzled-source global_load_lds, balanced q-tile
// pairs (t, 31-t) -> every block 33 phases. O aliases Q.
// ---------------------------------------------------------------------------
__global__ __launch_bounds__(256, 2) void flash_attn(
    const unsigned short* __restrict__ Q, const unsigned short* __restrict__ K,
    const unsigned short* __restrict__ Vt, unsigned short* __restrict__ O) {
  __shared__ __align__(16) unsigned short k_lds[2][64 * 64];
  __shared__ __align__(16) unsigned short v_lds[2][64 * 64];
  __shared__ __align__(16) unsigned short p_lds[4][16 * 64];

  const int bid = blockIdx.x;
  const int grp = bid & 7;              // XCD group: 4 (b,h) pairs each
  const int i = bid >> 3;               // 0..63
  const int bh = grp * 4 + (i & 3);
  const int b = bh >> 3, h = bh & 7;
  const int t = i >> 2;                 // 0..15 -> q-tile pair (t, 31-t)
  const int qtA = t, qtB = 31 - t;
  const int q0A = qtA * 64, q0B = qtB * 64;

  const int tid = threadIdx.x;
  const int w = tid >> 6, lane = tid & 63;
  const int r = lane & 15, g = lane >> 4;
  const int swz = (r & 7) << 3;

  const unsigned short* Qb = Q + (size_t)b * D + h * NH;
  const unsigned short* Kb = K + (size_t)b * D + h * NH;
  const unsigned short* Vb = Vt + ((size_t)(b * H + h) * NH) * SL;
  unsigned short* Ob = O + (size_t)b * D + h * NH;
  unsigned short* pw = &p_lds[w][0];

  auto STAGE = [&](int kt, int bsel) {
    unsigned short* kl = &k_lds[bsel][0];
    unsigned short* vl = &v_lds[bsel][0];
#pragma unroll
    for (int j = 0; j < 2; ++j) {
      int c = j * 256 + tid;
      int row = c >> 3, c8 = (c & 7) ^ (row & 7);
      gl16(&Kb[(size_t)(kt * 64 + row) * (BS * D) + c8 * 8], &kl[c * 8]);
      gl16(&Vb[(size_t)row * SL + kt * 64 + c8 * 8], &vl[c * 8]);
    }
  };

  STAGE(0, 0);

  short8 qfA[2], qfB[2];
#pragma unroll
  for (int kk = 0; kk < 2; ++kk) {
    qfA[kk] = *reinterpret_cast<const short8*>(
        &Qb[(size_t)(q0A + w * 16 + r) * (BS * D) + kk * 32 + g * 8]);
    qfB[kk] = *reinterpret_cast<const short8*>(
        &Qb[(size_t)(q0B + w * 16 + r) * (BS * D) + kk * 32 + g * 8]);
  }

  f32x4 oa[4];
  float mr, lr;
  auto reset_acc = [&]() {
#pragma unroll
    for (int n = 0; n < 4; ++n) oa[n] = f32x4{0.f, 0.f, 0.f, 0.f};
    mr = -1e30f; lr = 0.f;
  };
  reset_acc();

  auto compute = [&](int q0w, int kt, bool diag, short8(&qf)[2], int bsel) {
    const unsigned short* kl = &k_lds[bsel][0];
    const unsigned short* vl = &v_lds[bsel][0];
    short8 kf[2][4], vt[2][4];
#pragma unroll
    for (int kk = 0; kk < 2; ++kk)
#pragma unroll
      for (int n = 0; n < 4; ++n)
        kf[kk][n] = *reinterpret_cast<const short8*>(
            &kl[(n * 16 + r) * 64 + (((kk * 4 + g) ^ (r & 7)) * 8)]);

    f32x4 s[4];
#pragma unroll
    for (int n = 0; n < 4; ++n) s[n] = f32x4{0.f, 0.f, 0.f, 0.f};
#pragma unroll
    for (int kk = 0; kk < 2; ++kk) {
      __builtin_amdgcn_s_setprio(1);
#pragma unroll
      for (int n = 0; n < 4; ++n)
        s[n] = __builtin_amdgcn_mfma_f32_16x16x32_bf16(kf[kk][n], qf[kk], s[n], 0, 0, 0);
      __builtin_amdgcn_s_setprio(0);
    }

#pragma unroll
    for (int kk = 0; kk < 2; ++kk)
#pragma unroll
      for (int n = 0; n < 4; ++n)
        vt[kk][n] = *reinterpret_cast<const short8*>(
            &vl[(n * 16 + r) * 64 + (((kk * 4 + g) ^ (r & 7)) * 8)]);

    if (diag) {
      int qrow = q0w + r;
#pragma unroll
      for (int n = 0; n < 4; ++n)
#pragma unroll
        for (int rr = 0; rr < 4; ++rr)
          if (kt * 64 + n * 16 + g * 4 + rr > qrow) s[n][rr] = -1e30f;
    }

    float mx = s[0][0];
#pragma unroll
    for (int n = 0; n < 4; ++n)
#pragma unroll
      for (int rr = 0; rr < 4; ++rr)
        if (n | rr) mx = fmaxf(mx, s[n][rr]);
    mx = fmaxf(mx, __shfl_xor(mx, 16));
    mx = fmaxf(mx, __shfl_xor(mx, 32));
    bool need = __any(mx > mr + 8.f);
    float mold = mr;
    float mnew = need ? fmaxf(mold, mx) : mold;
    float ps = 0.f;
#pragma unroll
    for (int n = 0; n < 4; ++n)
#pragma unroll
      for (int rr = 0; rr < 4; ++rr) {
        float p = fast_exp2(s[n][rr] - mnew);
        s[n][rr] = p;
        ps += p;
      }
    ps += __shfl_xor(ps, 16);
    ps += __shfl_xor(ps, 32);
    if (need) {
      float sf = fast_exp2(mold - mnew);
      mr = mnew;
      lr = lr * sf + ps;
#pragma unroll
      for (int n = 0; n < 4; ++n) oa[n] *= sf;
    } else {
      lr += ps;
    }

#pragma unroll
    for (int n = 0; n < 4; ++n) {
      uint2v pk;
      pk.x = cvt_pk_bf16(s[n][0], s[n][1]);
      pk.y = cvt_pk_bf16(s[n][2], s[n][3]);
      *reinterpret_cast<uint2v*>(&pw[r * 64 + ((n * 16 + g * 4) ^ swz)]) = pk;
    }
    asm volatile("s_waitcnt lgkmcnt(0)" ::: "memory");
    __builtin_amdgcn_sched_barrier(0);

    short8 pf[2];
#pragma unroll
    for (int kk = 0; kk < 2; ++kk)
      pf[kk] = *reinterpret_cast<const short8*>(
          &pw[r * 64 + (((kk * 4 + g) ^ (r & 7)) * 8)]);
#pragma unroll
    for (int kk = 0; kk < 2; ++kk) {
      __builtin_amdgcn_s_setprio(1);
#pragma unroll
      for (int n = 0; n < 4; ++n)
        oa[n] = __builtin_amdgcn_mfma_f32_16x16x32_bf16(vt[kk][n], pf[kk], oa[n], 0, 0, 0);
      __builtin_amdgcn_s_setprio(0);
    }
  };

  auto finalize = [&](int q0) {
    float inv = 1.0f / lr;
#pragma unroll
    for (int n = 0; n < 4; ++n) {
      uint2v pk;
      pk.x = cvt_pk_bf16(oa[n][0] * inv, oa[n][1] * inv);
      pk.y = cvt_pk_bf16(oa[n][2] * inv, oa[n][3] * inv);
      *reinterpret_cast<uint2v*>(&pw[r * 64 + ((n * 16 + g * 4) ^ swz)]) = pk;
    }
    asm volatile("s_waitcnt lgkmcnt(0)" ::: "memory");
    __builtin_amdgcn_sched_barrier(0);
#pragma unroll
    for (int i2 = 0; i2 < 2; ++i2) {
      int c = i2 * 64 + lane;
      int row = c >> 3, c8 = c & 7;
      short8 v = *reinterpret_cast<const short8*>(&pw[row * 64 + c8 * 8]);
      *reinterpret_cast<short8*>(
          &Ob[(size_t)(q0 + w * 16 + row) * (BS * D) + ((c8 ^ (row & 7)) * 8)]) = v;
    }
  };

  int ph = 0;
  for (int kt = 0; kt <= qtA; ++kt, ++ph) {
    asm volatile("s_waitcnt vmcnt(0)" ::: "memory");
    __builtin_amdgcn_s_barrier();
    __builtin_amdgcn_sched_barrier(0);
    int np = ph + 1;
    if (np < 33) STAGE(np <= qtA ? np : np - qtA - 1, np & 1);
    compute(q0A + w * 16, kt, kt == qtA, qfA, ph & 1);
  }
  finalize(q0A);
  reset_acc();
  for (int kt = 0; kt <= qtB; ++kt, ++ph) {
    asm volatile("s_waitcnt vmcnt(0)" ::: "memory");
    __builtin_amdgcn_s_barrier();
    __builtin_amdgcn_sched_barrier(0);
    int np = ph + 1;
    if (np < 33) STAGE(np - qtA - 1, np & 1);
    compute(q0B + w * 16, kt, kt == qtB, qfB, ph & 1);
  }
  finalize(q0B);
}

// ---------------------------------------------------------------------------
extern "C" void kernel_launch(void* const* d_in, const int* in_sizes, int n_in,
                              void* d_out, int out_size, void* d_ws, size_t ws_size,
                              hipStream_t stream) {
  const float* x  = (const float*)d_in[0];
  const float* kx = (const float*)d_in[1];
  const float* vx = (const float*)d_in[2];
  const float* Wq = (const float*)d_in[3];
  const float* bq = (const float*)d_in[4];
  const float* Wk = (const float*)d_in[5];
  const float* bk = (const float*)d_in[6];
  const float* Wv = (const float*)d_in[7];
  const float* bv = (const float*)d_in[8];
  const float* Wo = (const float*)d_in[9];
  const float* bo = (const float*)d_in[10];

  // workspace (bf16), 26 MB: qb (attn-out aliases) | kb | vtb | wtb (2 MB)
  unsigned short* ws = (unsigned short*)d_ws;
  unsigned short* qb  = ws;
  unsigned short* kb  = ws + (size_t)M_ROWS * D;
  unsigned short* vtb = ws + (size_t)M_ROWS * D * 2;
  unsigned short* wtb = ws + (size_t)M_ROWS * D * 3;

  prep_wt<<<dim3(256), dim3(256), 0, stream>>>(Wq, Wk, Wv, Wo, wtb);
  qkv_gemm<<<dim3(64, 4, 3), dim3(256), 0, stream>>>(x, kx, vx, wtb, bq, bk, bv,
                                                     qb, kb, vtb);
  flash_attn<<<dim3(512), dim3(256), 0, stream>>>(qb, kb, vtb, qb);
  gemm_oproj<<<dim3(64, 4, 1), dim3(256), 0, stream>>>(qb, wtb + (size_t)3 * D * D,
                                                       bo, (float*)d_out);
}

// Round 8
// 86.805 us; speedup vs baseline: 3.0736x; 1.1188x over previous
//
#include <hip/hip_runtime.h>

typedef __attribute__((ext_vector_type(8))) short short8;
typedef __attribute__((ext_vector_type(4))) short short4v;
typedef __attribute__((ext_vector_type(4))) float f32x4;
typedef __attribute__((ext_vector_type(2))) unsigned int uint2v;

constexpr int SL = 2048, BS = 4, D = 512, H = 8, NH = 64;
constexpr int M_ROWS = SL * BS;   // 8192
constexpr float SCALE = 0.125f;   // 1/sqrt(64)
constexpr float LOG2E = 1.44269504088896340736f;

__device__ __forceinline__ unsigned short f2bf(float f) {
  union { float f; unsigned u; } v; v.f = f;
  unsigned r = v.u + 0x7FFFu + ((v.u >> 16) & 1u);
  return (unsigned short)(r >> 16);
}

__device__ __forceinline__ unsigned cvt_pk_bf16(float a, float b) {
  unsigned r;
  asm("v_cvt_pk_bf16_f32 %0, %1, %2" : "=v"(r) : "v"(a), "v"(b));
  return r;
}

__device__ __forceinline__ float fast_exp2(float x) {
  float r;
  asm("v_exp_f32 %0, %1" : "=v"(r) : "v"(x));
  return r;
}

// async global->LDS, 16B per lane; LDS dest = wave-uniform base + lane*16
__device__ __forceinline__ void gl16(const void* g, void* l) {
  __builtin_amdgcn_global_load_lds(
      (const __attribute__((address_space(1))) unsigned int*)g,
      (__attribute__((address_space(3))) unsigned int*)l, 16, 0, 0);
}

// ---------------------------------------------------------------------------
// prep: W[512][512] f32 row-major -> W^T[n][k] bf16, LDS-tiled 64x64.
// ---------------------------------------------------------------------------
__global__ __launch_bounds__(256) void prep_wt(
    const float* __restrict__ w0, const float* __restrict__ w1,
    const float* __restrict__ w2, const float* __restrict__ w3,
    unsigned short* __restrict__ wtb) {
  __shared__ float tl[64][65];
  const int tid = threadIdx.x;
  const int wi = blockIdx.x >> 6, t6 = blockIdx.x & 63;
  const int k0 = (t6 >> 3) * 64, n0 = (t6 & 7) * 64;
  const float* W = wi == 0 ? w0 : (wi == 1 ? w1 : (wi == 2 ? w2 : w3));
  unsigned short* WT = wtb + (size_t)wi * D * D;

#pragma unroll
  for (int i = 0; i < 4; ++i) {
    int k = (tid >> 4) + i * 16, n4 = (tid & 15) * 4;
    f32x4 v = *reinterpret_cast<const f32x4*>(&W[(size_t)(k0 + k) * D + n0 + n4]);
#pragma unroll
    for (int j = 0; j < 4; ++j) tl[n4 + j][k] = v[j];
  }
  __syncthreads();
#pragma unroll
  for (int i = 0; i < 2; ++i) {
    int n = (tid >> 3) + i * 32, k8 = (tid & 7) * 8;
    union { unsigned u[4]; short8 s; } pk;
#pragma unroll
    for (int j = 0; j < 4; ++j)
      pk.u[j] = cvt_pk_bf16(tl[n][k8 + 2 * j], tl[n][k8 + 2 * j + 1]);
    *reinterpret_cast<short8*>(&WT[(size_t)(n0 + n) * D + k0 + k8]) = pk.s;
  }
}

// ---------------------------------------------------------------------------
// GEMM v2: 128x128 tile, BK=64, DOUBLE-BUFFERED 2-phase pipeline with counted
// vmcnt (stage t+1 issued before compute t; never drain mid-step), XOR-swizzled
// LDS (pre-swizzled global source + swizzled ds_read -> conflict-free b128).
// smem = 64 KB: [buf][A|B][8192 u16]. V^T epilogue bounces through LDS for
// coalesced 16B stores.
// ---------------------------------------------------------------------------
template <bool A_BF16, int OUT_MODE>
__device__ __forceinline__ void gemm_bt_body(const void* __restrict__ Ap,
                                             const unsigned short* __restrict__ BT,
                                             const float* __restrict__ bias,
                                             void* __restrict__ Outp, float scale,
                                             unsigned short* smem) {
  const int tid = threadIdx.x;
  const int brow = blockIdx.x * 128;
  const int bcol = blockIdx.y * 128;
  const int lane = tid & 63;
  const int wid = tid >> 6;
  const int wr = (wid >> 1) * 64;
  const int wc = (wid & 1) * 64;
  const int r = lane & 15;
  const int g = lane >> 4;

  auto a_buf = [&](int b) { return smem + b * 16384; };
  auto b_buf = [&](int b) { return smem + b * 16384 + 8192; };

  f32x4 acc[4][4];
#pragma unroll
  for (int m = 0; m < 4; ++m)
#pragma unroll
    for (int n = 0; n < 4; ++n) acc[m][n] = f32x4{0.f, 0.f, 0.f, 0.f};

  // stage helpers: chunk c = j*256+tid; row = c>>3; source col pre-swizzled
  auto STAGE_B = [&](int kt, int bsel) {
    unsigned short* bl = b_buf(bsel);
#pragma unroll
    for (int j = 0; j < 4; ++j) {
      int c = j * 256 + tid;
      int row = c >> 3, c8 = (c & 7) ^ (row & 7);
      gl16(&BT[(size_t)(bcol + row) * D + kt + c8 * 8], &bl[c * 8]);
    }
  };
  auto STAGE_A_LDS = [&](int kt, int bsel) {
    const unsigned short* A = (const unsigned short*)Ap;
    unsigned short* al = a_buf(bsel);
#pragma unroll
    for (int j = 0; j < 4; ++j) {
      int c = j * 256 + tid;
      int row = c >> 3, c8 = (c & 7) ^ (row & 7);
      gl16(&A[(size_t)(brow + row) * D + kt + c8 * 8], &al[c * 8]);
    }
  };
  auto A_LOAD = [&](int kt, f32x4 (&va)[4][2]) {
    const float* A = (const float*)Ap;
#pragma unroll
    for (int j = 0; j < 4; ++j) {
      int c = j * 256 + tid;
      int row = c >> 3, c8 = (c & 7) ^ (row & 7);
      const float* ap = &A[(size_t)(brow + row) * D + kt + c8 * 8];
      va[j][0] = *reinterpret_cast<const f32x4*>(ap);
      va[j][1] = *reinterpret_cast<const f32x4*>(ap + 4);
    }
  };
  auto A_WRITE = [&](f32x4 (&va)[4][2], int bsel) {
    unsigned short* al = a_buf(bsel);
#pragma unroll
    for (int j = 0; j < 4; ++j) {
      int c = j * 256 + tid;
      union { unsigned u[4]; short8 s; } pk;
      pk.u[0] = cvt_pk_bf16(va[j][0][0], va[j][0][1]);
      pk.u[1] = cvt_pk_bf16(va[j][0][2], va[j][0][3]);
      pk.u[2] = cvt_pk_bf16(va[j][1][0], va[j][1][1]);
      pk.u[3] = cvt_pk_bf16(va[j][1][2], va[j][1][3]);
      *reinterpret_cast<short8*>(&al[c * 8]) = pk.s;
    }
  };
  auto COMPUTE = [&](int bsel) {
    const unsigned short* al = a_buf(bsel);
    const unsigned short* bl = b_buf(bsel);
#pragma unroll
    for (int kk2 = 0; kk2 < 2; ++kk2) {
      short8 af[4], bfr[4];
#pragma unroll
      for (int m = 0; m < 4; ++m)
        af[m] = *reinterpret_cast<const short8*>(
            &al[(wr + m * 16 + r) * 64 + (((kk2 * 4 + g) ^ (r & 7)) * 8)]);
#pragma unroll
      for (int n = 0; n < 4; ++n)
        bfr[n] = *reinterpret_cast<const short8*>(
            &bl[(wc + n * 16 + r) * 64 + (((kk2 * 4 + g) ^ (r & 7)) * 8)]);
      __builtin_amdgcn_s_setprio(1);
#pragma unroll
      for (int m = 0; m < 4; ++m)
#pragma unroll
        for (int n = 0; n < 4; ++n)
          acc[m][n] = __builtin_amdgcn_mfma_f32_16x16x32_bf16(af[m], bfr[n], acc[m][n], 0, 0, 0);
      __builtin_amdgcn_s_setprio(0);
    }
  };

  // ---- prologue: stage tile 0 (latency exposed once) ----
  if (A_BF16) {
    STAGE_A_LDS(0, 0);
    STAGE_B(0, 0);
    asm volatile("s_waitcnt vmcnt(0)" ::: "memory");
  } else {
    f32x4 va[4][2];
    A_LOAD(0, va);           // 8 vmem (oldest)
    STAGE_B(0, 0);           // 4 gl16 (newest)
    asm volatile("s_waitcnt vmcnt(4)" ::: "memory");  // A loads done
    A_WRITE(va, 0);
    asm volatile("s_waitcnt vmcnt(0) lgkmcnt(0)" ::: "memory");
  }
  __builtin_amdgcn_s_barrier();

  // ---- 8-step pipelined K-loop ----
#pragma unroll
  for (int t = 0; t < 8; ++t) {
    const int cur = t & 1, nxt = cur ^ 1;
    const int ktn = (t + 1) * 64;
    __builtin_amdgcn_sched_barrier(0);
    f32x4 va[4][2];
    if (t < 7) {
      if (A_BF16) {
        STAGE_A_LDS(ktn, nxt);
        STAGE_B(ktn, nxt);
      } else {
        A_LOAD(ktn, va);     // issue early; hides under COMPUTE
        STAGE_B(ktn, nxt);
      }
    }
    __builtin_amdgcn_sched_barrier(0);
    COMPUTE(cur);
    if (t < 7) {
      if (!A_BF16) {
        asm volatile("s_waitcnt vmcnt(4)" ::: "memory");  // A f32 loads back
        A_WRITE(va, nxt);
      }
      asm volatile("s_waitcnt vmcnt(0) lgkmcnt(0)" ::: "memory");
      __builtin_amdgcn_s_barrier();
    }
  }

  // ---- epilogue ----
  if (OUT_MODE == 2) {
    // V^T: bounce through LDS (buf0 area; final compute used buf1) for
    // coalesced 16B stores. sc layout: [col 0..127][16 chunks of 8 u16],
    // chunk index xor-swizzled by (col&7).
    unsigned short* sc = smem;
    const int wr4 = wr >> 2;
#pragma unroll
    for (int m = 0; m < 4; ++m)
#pragma unroll
      for (int n = 0; n < 4; ++n) {
        int col = wc + n * 16 + r;
        float bv = bias[bcol + col];
        int sl = wr4 + m * 4 + g;                       // 0..31
#pragma unroll
        for (int rr = 0; rr < 4; ++rr) {
          int c = (rr * 4 + (sl >> 3)) ^ (col & 7);
          sc[col * 128 + c * 8 + (sl & 7)] = f2bf((acc[m][n][rr] + bv) * scale);
        }
      }
    asm volatile("s_waitcnt lgkmcnt(0)" ::: "memory");
    __builtin_amdgcn_s_barrier();
    unsigned short* VT = (unsigned short*)Outp;
#pragma unroll
    for (int i2 = 0; i2 < 2; ++i2) {
      int q = tid * 2 + i2;
      int col = q >> 2, bb = q & 3;
      int gcol = bcol + col, hh = gcol >> 6, nh = gcol & 63;
      size_t gbase = (((size_t)bb * H + hh) * NH + nh) * SL + (brow >> 2);
#pragma unroll
      for (int j = 0; j < 4; ++j) {
        short8 v = *reinterpret_cast<const short8*>(
            &sc[col * 128 + (((bb * 4 + j) ^ (col & 7)) * 8)]);
        *reinterpret_cast<short8*>(&VT[gbase + j * 8]) = v;
      }
    }
  } else {
#pragma unroll
    for (int m = 0; m < 4; ++m)
#pragma unroll
      for (int n = 0; n < 4; ++n) {
        int gcol = bcol + wc + n * 16 + r;
        float bv = bias[gcol];
#pragma unroll
        for (int rr = 0; rr < 4; ++rr) {
          int grow = brow + wr + m * 16 + g * 4 + rr;
          float val = (acc[m][n][rr] + bv) * scale;
          if (OUT_MODE == 0)
            ((float*)Outp)[(size_t)grow * D + gcol] = val;
          else
            ((unsigned short*)Outp)[(size_t)grow * D + gcol] = f2bf(val);
        }
      }
  }
}

__global__ __launch_bounds__(256, 2) void qkv_gemm(
    const float* __restrict__ x0, const float* __restrict__ x1, const float* __restrict__ x2,
    const unsigned short* __restrict__ wtb,
    const float* __restrict__ b0, const float* __restrict__ b1, const float* __restrict__ b2,
    unsigned short* __restrict__ q_out, unsigned short* __restrict__ k_out,
    unsigned short* __restrict__ vt_out) {
  __shared__ __align__(16) unsigned short smem[2 * 16384];
  int z = blockIdx.z;
  const float* X = z == 0 ? x0 : (z == 1 ? x1 : x2);
  const unsigned short* WT = wtb + (size_t)z * D * D;
  const float* B = z == 0 ? b0 : (z == 1 ? b1 : b2);
  float scale = (z == 0) ? SCALE * LOG2E : 1.0f;
  if (z == 2)
    gemm_bt_body<false, 2>(X, WT, B, vt_out, scale, smem);
  else
    gemm_bt_body<false, 1>(X, WT, B, z == 0 ? q_out : k_out, scale, smem);
}

__global__ __launch_bounds__(256, 2) void gemm_oproj(
    const unsigned short* __restrict__ A, const unsigned short* __restrict__ WT,
    const float* __restrict__ B, float* __restrict__ Outp) {
  __shared__ __align__(16) unsigned short smem[2 * 16384];
  gemm_bt_body<true, 0>(A, WT, B, Outp, 1.0f, smem);
}

// ---------------------------------------------------------------------------
// Flash attention v3 (unchanged from round 6).
// ---------------------------------------------------------------------------
__global__ __launch_bounds__(256, 2) void flash_attn(
    const unsigned short* __restrict__ Q, const unsigned short* __restrict__ K,
    const unsigned short* __restrict__ Vt, unsigned short* __restrict__ O) {
  __shared__ __align__(16) unsigned short k_lds[2][64 * 64];
  __shared__ __align__(16) unsigned short v_lds[2][64 * 64];
  __shared__ __align__(16) unsigned short p_lds[4][16 * 64];

  const int bid = blockIdx.x;
  const int grp = bid & 7;
  const int i = bid >> 3;
  const int bh = grp * 4 + (i & 3);
  const int b = bh >> 3, h = bh & 7;
  const int t = i >> 2;
  const int qtA = t, qtB = 31 - t;
  const int q0A = qtA * 64, q0B = qtB * 64;

  const int tid = threadIdx.x;
  const int w = tid >> 6, lane = tid & 63;
  const int r = lane & 15, g = lane >> 4;
  const int swz = (r & 7) << 3;

  const unsigned short* Qb = Q + (size_t)b * D + h * NH;
  const unsigned short* Kb = K + (size_t)b * D + h * NH;
  const unsigned short* Vb = Vt + ((size_t)(b * H + h) * NH) * SL;
  unsigned short* Ob = O + (size_t)b * D + h * NH;
  unsigned short* pw = &p_lds[w][0];

  auto STAGE = [&](int kt, int bsel) {
    unsigned short* kl = &k_lds[bsel][0];
    unsigned short* vl = &v_lds[bsel][0];
#pragma unroll
    for (int j = 0; j < 2; ++j) {
      int c = j * 256 + tid;
      int row = c >> 3, c8 = (c & 7) ^ (row & 7);
      gl16(&Kb[(size_t)(kt * 64 + row) * (BS * D) + c8 * 8], &kl[c * 8]);
      gl16(&Vb[(size_t)row * SL + kt * 64 + c8 * 8], &vl[c * 8]);
    }
  };

  STAGE(0, 0);

  short8 qfA[2], qfB[2];
#pragma unroll
  for (int kk = 0; kk < 2; ++kk) {
    qfA[kk] = *reinterpret_cast<const short8*>(
        &Qb[(size_t)(q0A + w * 16 + r) * (BS * D) + kk * 32 + g * 8]);
    qfB[kk] = *reinterpret_cast<const short8*>(
        &Qb[(size_t)(q0B + w * 16 + r) * (BS * D) + kk * 32 + g * 8]);
  }

  f32x4 oa[4];
  float mr, lr;
  auto reset_acc = [&]() {
#pragma unroll
    for (int n = 0; n < 4; ++n) oa[n] = f32x4{0.f, 0.f, 0.f, 0.f};
    mr = -1e30f; lr = 0.f;
  };
  reset_acc();

  auto compute = [&](int q0w, int kt, bool diag, short8(&qf)[2], int bsel) {
    const unsigned short* kl = &k_lds[bsel][0];
    const unsigned short* vl = &v_lds[bsel][0];
    short8 kf[2][4], vt[2][4];
#pragma unroll
    for (int kk = 0; kk < 2; ++kk)
#pragma unroll
      for (int n = 0; n < 4; ++n)
        kf[kk][n] = *reinterpret_cast<const short8*>(
            &kl[(n * 16 + r) * 64 + (((kk * 4 + g) ^ (r & 7)) * 8)]);

    f32x4 s[4];
#pragma unroll
    for (int n = 0; n < 4; ++n) s[n] = f32x4{0.f, 0.f, 0.f, 0.f};
#pragma unroll
    for (int kk = 0; kk < 2; ++kk) {
      __builtin_amdgcn_s_setprio(1);
#pragma unroll
      for (int n = 0; n < 4; ++n)
        s[n] = __builtin_amdgcn_mfma_f32_16x16x32_bf16(kf[kk][n], qf[kk], s[n], 0, 0, 0);
      __builtin_amdgcn_s_setprio(0);
    }

#pragma unroll
    for (int kk = 0; kk < 2; ++kk)
#pragma unroll
      for (int n = 0; n < 4; ++n)
        vt[kk][n] = *reinterpret_cast<const short8*>(
            &vl[(n * 16 + r) * 64 + (((kk * 4 + g) ^ (r & 7)) * 8)]);

    if (diag) {
      int qrow = q0w + r;
#pragma unroll
      for (int n = 0; n < 4; ++n)
#pragma unroll
        for (int rr = 0; rr < 4; ++rr)
          if (kt * 64 + n * 16 + g * 4 + rr > qrow) s[n][rr] = -1e30f;
    }

    float mx = s[0][0];
#pragma unroll
    for (int n = 0; n < 4; ++n)
#pragma unroll
      for (int rr = 0; rr < 4; ++rr)
        if (n | rr) mx = fmaxf(mx, s[n][rr]);
    mx = fmaxf(mx, __shfl_xor(mx, 16));
    mx = fmaxf(mx, __shfl_xor(mx, 32));
    bool need = __any(mx > mr + 8.f);
    float mold = mr;
    float mnew = need ? fmaxf(mold, mx) : mold;
    float ps = 0.f;
#pragma unroll
    for (int n = 0; n < 4; ++n)
#pragma unroll
      for (int rr = 0; rr < 4; ++rr) {
        float p = fast_exp2(s[n][rr] - mnew);
        s[n][rr] = p;
        ps += p;
      }
    ps += __shfl_xor(ps, 16);
    ps += __shfl_xor(ps, 32);
    if (need) {
      float sf = fast_exp2(mold - mnew);
      mr = mnew;
      lr = lr * sf + ps;
#pragma unroll
      for (int n = 0; n < 4; ++n) oa[n] *= sf;
    } else {
      lr += ps;
    }

#pragma unroll
    for (int n = 0; n < 4; ++n) {
      uint2v pk;
      pk.x = cvt_pk_bf16(s[n][0], s[n][1]);
      pk.y = cvt_pk_bf16(s[n][2], s[n][3]);
      *reinterpret_cast<uint2v*>(&pw[r * 64 + ((n * 16 + g * 4) ^ swz)]) = pk;
    }
    asm volatile("s_waitcnt lgkmcnt(0)" ::: "memory");
    __builtin_amdgcn_sched_barrier(0);

    short8 pf[2];
#pragma unroll
    for (int kk = 0; kk < 2; ++kk)
      pf[kk] = *reinterpret_cast<const short8*>(
          &pw[r * 64 + (((kk * 4 + g) ^ (r & 7)) * 8)]);
#pragma unroll
    for (int kk = 0; kk < 2; ++kk) {
      __builtin_amdgcn_s_setprio(1);
#pragma unroll
      for (int n = 0; n < 4; ++n)
        oa[n] = __builtin_amdgcn_mfma_f32_16x16x32_bf16(vt[kk][n], pf[kk], oa[n], 0, 0, 0);
      __builtin_amdgcn_s_setprio(0);
    }
  };

  auto finalize = [&](int q0) {
    float inv = 1.0f / lr;
#pragma unroll
    for (int n = 0; n < 4; ++n) {
      uint2v pk;
      pk.x = cvt_pk_bf16(oa[n][0] * inv, oa[n][1] * inv);
      pk.y = cvt_pk_bf16(oa[n][2] * inv, oa[n][3] * inv);
      *reinterpret_cast<uint2v*>(&pw[r * 64 + ((n * 16 + g * 4) ^ swz)]) = pk;
    }
    asm volatile("s_waitcnt lgkmcnt(0)" ::: "memory");
    __builtin_amdgcn_sched_barrier(0);
#pragma unroll
    for (int i2 = 0; i2 < 2; ++i2) {
      int c = i2 * 64 + lane;
      int row = c >> 3, c8 = c & 7;
      short8 v = *reinterpret_cast<const short8*>(&pw[row * 64 + c8 * 8]);
      *reinterpret_cast<short8*>(
          &Ob[(size_t)(q0 + w * 16 + row) * (BS * D) + ((c8 ^ (row & 7)) * 8)]) = v;
    }
  };

  int ph = 0;
  for (int kt = 0; kt <= qtA; ++kt, ++ph) {
    asm volatile("s_waitcnt vmcnt(0)" ::: "memory");
    __builtin_amdgcn_s_barrier();
    __builtin_amdgcn_sched_barrier(0);
    int np = ph + 1;
    if (np < 33) STAGE(np <= qtA ? np : np - qtA - 1, np & 1);
    compute(q0A + w * 16, kt, kt == qtA, qfA, ph & 1);
  }
  finalize(q0A);
  reset_acc();
  for (int kt = 0; kt <= qtB; ++kt, ++ph) {
    asm volatile("s_waitcnt vmcnt(0)" ::: "memory");
    __builtin_amdgcn_s_barrier();
    __builtin_amdgcn_sched_barrier(0);
    int np = ph + 1;
    if (np < 33) STAGE(np - qtA - 1, np & 1);
    compute(q0B + w * 16, kt, kt == qtB, qfB, ph & 1);
  }
  finalize(q0B);
}

// ---------------------------------------------------------------------------
extern "C" void kernel_launch(void* const* d_in, const int* in_sizes, int n_in,
                              void* d_out, int out_size, void* d_ws, size_t ws_size,
                              hipStream_t stream) {
  const float* x  = (const float*)d_in[0];
  const float* kx = (const float*)d_in[1];
  const float* vx = (const float*)d_in[2];
  const float* Wq = (const float*)d_in[3];
  const float* bq = (const float*)d_in[4];
  const float* Wk = (const float*)d_in[5];
  const float* bk = (const float*)d_in[6];
  const float* Wv = (const float*)d_in[7];
  const float* bv = (const float*)d_in[8];
  const float* Wo = (const float*)d_in[9];
  const float* bo = (const float*)d_in[10];

  // workspace (bf16), 26 MB: qb (attn-out aliases) | kb | vtb | wtb (2 MB)
  unsigned short* ws = (unsigned short*)d_ws;
  unsigned short* qb  = ws;
  unsigned short* kb  = ws + (size_t)M_ROWS * D;
  unsigned short* vtb = ws + (size_t)M_ROWS * D * 2;
  unsigned short* wtb = ws + (size_t)M_ROWS * D * 3;

  prep_wt<<<dim3(256), dim3(256), 0, stream>>>(Wq, Wk, Wv, Wo, wtb);
  qkv_gemm<<<dim3(64, 4, 3), dim3(256), 0, stream>>>(x, kx, vx, wtb, bq, bk, bv,
                                                     qb, kb, vtb);
  flash_attn<<<dim3(512), dim3(256), 0, stream>>>(qb, kb, vtb, qb);
  gemm_oproj<<<dim3(64, 4, 1), dim3(256), 0, stream>>>(qb, wtb + (size_t)3 * D * D,
                                                       bo, (float*)d_out);
}

// Round 9
// 85.193 us; speedup vs baseline: 3.1317x; 1.0189x over previous
//
#include <hip/hip_runtime.h>

typedef __attribute__((ext_vector_type(8))) short short8;
typedef __attribute__((ext_vector_type(4))) short short4v;
typedef __attribute__((ext_vector_type(4))) float f32x4;
typedef __attribute__((ext_vector_type(2))) unsigned int uint2v;

constexpr int SL = 2048, BS = 4, D = 512, H = 8, NH = 64;
constexpr int M_ROWS = SL * BS;   // 8192
constexpr float SCALE = 0.125f;   // 1/sqrt(64)
constexpr float LOG2E = 1.44269504088896340736f;

__device__ __forceinline__ unsigned short f2bf(float f) {
  union { float f; unsigned u; } v; v.f = f;
  unsigned r = v.u + 0x7FFFu + ((v.u >> 16) & 1u);
  return (unsigned short)(r >> 16);
}

__device__ __forceinline__ unsigned cvt_pk_bf16(float a, float b) {
  unsigned r;
  asm("v_cvt_pk_bf16_f32 %0, %1, %2" : "=v"(r) : "v"(a), "v"(b));
  return r;
}

__device__ __forceinline__ float fast_exp2(float x) {
  float r;
  asm("v_exp_f32 %0, %1" : "=v"(r) : "v"(x));
  return r;
}

// async global->LDS, 16B per lane; LDS dest = wave-uniform base + lane*16
__device__ __forceinline__ void gl16(const void* g, void* l) {
  __builtin_amdgcn_global_load_lds(
      (const __attribute__((address_space(1))) unsigned int*)g,
      (__attribute__((address_space(3))) unsigned int*)l, 16, 0, 0);
}

// ---------------------------------------------------------------------------
// prep: W[512][512] f32 row-major -> W^T[n][k] bf16, LDS-tiled 64x64.
// ---------------------------------------------------------------------------
__global__ __launch_bounds__(256) void prep_wt(
    const float* __restrict__ w0, const float* __restrict__ w1,
    const float* __restrict__ w2, const float* __restrict__ w3,
    unsigned short* __restrict__ wtb) {
  __shared__ float tl[64][65];
  const int tid = threadIdx.x;
  const int wi = blockIdx.x >> 6, t6 = blockIdx.x & 63;
  const int k0 = (t6 >> 3) * 64, n0 = (t6 & 7) * 64;
  const float* W = wi == 0 ? w0 : (wi == 1 ? w1 : (wi == 2 ? w2 : w3));
  unsigned short* WT = wtb + (size_t)wi * D * D;

#pragma unroll
  for (int i = 0; i < 4; ++i) {
    int k = (tid >> 4) + i * 16, n4 = (tid & 15) * 4;
    f32x4 v = *reinterpret_cast<const f32x4*>(&W[(size_t)(k0 + k) * D + n0 + n4]);
#pragma unroll
    for (int j = 0; j < 4; ++j) tl[n4 + j][k] = v[j];
  }
  __syncthreads();
#pragma unroll
  for (int i = 0; i < 2; ++i) {
    int n = (tid >> 3) + i * 32, k8 = (tid & 7) * 8;
    union { unsigned u[4]; short8 s; } pk;
#pragma unroll
    for (int j = 0; j < 4; ++j)
      pk.u[j] = cvt_pk_bf16(tl[n][k8 + 2 * j], tl[n][k8 + 2 * j + 1]);
    *reinterpret_cast<short8*>(&WT[(size_t)(n0 + n) * D + k0 + k8]) = pk.s;
  }
}

// ---------------------------------------------------------------------------
// GEMM v2 (unchanged from round 8): double-buffered 2-phase pipeline, counted
// vmcnt, XOR-swizzled LDS, V^T epilogue via LDS bounce.
// ---------------------------------------------------------------------------
template <bool A_BF16, int OUT_MODE>
__device__ __forceinline__ void gemm_bt_body(const void* __restrict__ Ap,
                                             const unsigned short* __restrict__ BT,
                                             const float* __restrict__ bias,
                                             void* __restrict__ Outp, float scale,
                                             unsigned short* smem) {
  const int tid = threadIdx.x;
  const int brow = blockIdx.x * 128;
  const int bcol = blockIdx.y * 128;
  const int lane = tid & 63;
  const int wid = tid >> 6;
  const int wr = (wid >> 1) * 64;
  const int wc = (wid & 1) * 64;
  const int r = lane & 15;
  const int g = lane >> 4;

  auto a_buf = [&](int b) { return smem + b * 16384; };
  auto b_buf = [&](int b) { return smem + b * 16384 + 8192; };

  f32x4 acc[4][4];
#pragma unroll
  for (int m = 0; m < 4; ++m)
#pragma unroll
    for (int n = 0; n < 4; ++n) acc[m][n] = f32x4{0.f, 0.f, 0.f, 0.f};

  auto STAGE_B = [&](int kt, int bsel) {
    unsigned short* bl = b_buf(bsel);
#pragma unroll
    for (int j = 0; j < 4; ++j) {
      int c = j * 256 + tid;
      int row = c >> 3, c8 = (c & 7) ^ (row & 7);
      gl16(&BT[(size_t)(bcol + row) * D + kt + c8 * 8], &bl[c * 8]);
    }
  };
  auto STAGE_A_LDS = [&](int kt, int bsel) {
    const unsigned short* A = (const unsigned short*)Ap;
    unsigned short* al = a_buf(bsel);
#pragma unroll
    for (int j = 0; j < 4; ++j) {
      int c = j * 256 + tid;
      int row = c >> 3, c8 = (c & 7) ^ (row & 7);
      gl16(&A[(size_t)(brow + row) * D + kt + c8 * 8], &al[c * 8]);
    }
  };
  auto A_LOAD = [&](int kt, f32x4 (&va)[4][2]) {
    const float* A = (const float*)Ap;
#pragma unroll
    for (int j = 0; j < 4; ++j) {
      int c = j * 256 + tid;
      int row = c >> 3, c8 = (c & 7) ^ (row & 7);
      const float* ap = &A[(size_t)(brow + row) * D + kt + c8 * 8];
      va[j][0] = *reinterpret_cast<const f32x4*>(ap);
      va[j][1] = *reinterpret_cast<const f32x4*>(ap + 4);
    }
  };
  auto A_WRITE = [&](f32x4 (&va)[4][2], int bsel) {
    unsigned short* al = a_buf(bsel);
#pragma unroll
    for (int j = 0; j < 4; ++j) {
      int c = j * 256 + tid;
      union { unsigned u[4]; short8 s; } pk;
      pk.u[0] = cvt_pk_bf16(va[j][0][0], va[j][0][1]);
      pk.u[1] = cvt_pk_bf16(va[j][0][2], va[j][0][3]);
      pk.u[2] = cvt_pk_bf16(va[j][1][0], va[j][1][1]);
      pk.u[3] = cvt_pk_bf16(va[j][1][2], va[j][1][3]);
      *reinterpret_cast<short8*>(&al[c * 8]) = pk.s;
    }
  };
  auto COMPUTE = [&](int bsel) {
    const unsigned short* al = a_buf(bsel);
    const unsigned short* bl = b_buf(bsel);
#pragma unroll
    for (int kk2 = 0; kk2 < 2; ++kk2) {
      short8 af[4], bfr[4];
#pragma unroll
      for (int m = 0; m < 4; ++m)
        af[m] = *reinterpret_cast<const short8*>(
            &al[(wr + m * 16 + r) * 64 + (((kk2 * 4 + g) ^ (r & 7)) * 8)]);
#pragma unroll
      for (int n = 0; n < 4; ++n)
        bfr[n] = *reinterpret_cast<const short8*>(
            &bl[(wc + n * 16 + r) * 64 + (((kk2 * 4 + g) ^ (r & 7)) * 8)]);
      __builtin_amdgcn_s_setprio(1);
#pragma unroll
      for (int m = 0; m < 4; ++m)
#pragma unroll
        for (int n = 0; n < 4; ++n)
          acc[m][n] = __builtin_amdgcn_mfma_f32_16x16x32_bf16(af[m], bfr[n], acc[m][n], 0, 0, 0);
      __builtin_amdgcn_s_setprio(0);
    }
  };

  if (A_BF16) {
    STAGE_A_LDS(0, 0);
    STAGE_B(0, 0);
    asm volatile("s_waitcnt vmcnt(0)" ::: "memory");
  } else {
    f32x4 va[4][2];
    A_LOAD(0, va);
    STAGE_B(0, 0);
    asm volatile("s_waitcnt vmcnt(4)" ::: "memory");
    A_WRITE(va, 0);
    asm volatile("s_waitcnt vmcnt(0) lgkmcnt(0)" ::: "memory");
  }
  __builtin_amdgcn_s_barrier();

#pragma unroll
  for (int t = 0; t < 8; ++t) {
    const int cur = t & 1, nxt = cur ^ 1;
    const int ktn = (t + 1) * 64;
    __builtin_amdgcn_sched_barrier(0);
    f32x4 va[4][2];
    if (t < 7) {
      if (A_BF16) {
        STAGE_A_LDS(ktn, nxt);
        STAGE_B(ktn, nxt);
      } else {
        A_LOAD(ktn, va);
        STAGE_B(ktn, nxt);
      }
    }
    __builtin_amdgcn_sched_barrier(0);
    COMPUTE(cur);
    if (t < 7) {
      if (!A_BF16) {
        asm volatile("s_waitcnt vmcnt(4)" ::: "memory");
        A_WRITE(va, nxt);
      }
      asm volatile("s_waitcnt vmcnt(0) lgkmcnt(0)" ::: "memory");
      __builtin_amdgcn_s_barrier();
    }
  }

  if (OUT_MODE == 2) {
    unsigned short* sc = smem;
    const int wr4 = wr >> 2;
#pragma unroll
    for (int m = 0; m < 4; ++m)
#pragma unroll
      for (int n = 0; n < 4; ++n) {
        int col = wc + n * 16 + r;
        float bv = bias[bcol + col];
        int sl = wr4 + m * 4 + g;
#pragma unroll
        for (int rr = 0; rr < 4; ++rr) {
          int c = (rr * 4 + (sl >> 3)) ^ (col & 7);
          sc[col * 128 + c * 8 + (sl & 7)] = f2bf((acc[m][n][rr] + bv) * scale);
        }
      }
    asm volatile("s_waitcnt lgkmcnt(0)" ::: "memory");
    __builtin_amdgcn_s_barrier();
    unsigned short* VT = (unsigned short*)Outp;
#pragma unroll
    for (int i2 = 0; i2 < 2; ++i2) {
      int q = tid * 2 + i2;
      int col = q >> 2, bb = q & 3;
      int gcol = bcol + col, hh = gcol >> 6, nh = gcol & 63;
      size_t gbase = (((size_t)bb * H + hh) * NH + nh) * SL + (brow >> 2);
#pragma unroll
      for (int j = 0; j < 4; ++j) {
        short8 v = *reinterpret_cast<const short8*>(
            &sc[col * 128 + (((bb * 4 + j) ^ (col & 7)) * 8)]);
        *reinterpret_cast<short8*>(&VT[gbase + j * 8]) = v;
      }
    }
  } else {
#pragma unroll
    for (int m = 0; m < 4; ++m)
#pragma unroll
      for (int n = 0; n < 4; ++n) {
        int gcol = bcol + wc + n * 16 + r;
        float bv = bias[gcol];
#pragma unroll
        for (int rr = 0; rr < 4; ++rr) {
          int grow = brow + wr + m * 16 + g * 4 + rr;
          float val = (acc[m][n][rr] + bv) * scale;
          if (OUT_MODE == 0)
            ((float*)Outp)[(size_t)grow * D + gcol] = val;
          else
            ((unsigned short*)Outp)[(size_t)grow * D + gcol] = f2bf(val);
        }
      }
  }
}

__global__ __launch_bounds__(256, 2) void qkv_gemm(
    const float* __restrict__ x0, const float* __restrict__ x1, const float* __restrict__ x2,
    const unsigned short* __restrict__ wtb,
    const float* __restrict__ b0, const float* __restrict__ b1, const float* __restrict__ b2,
    unsigned short* __restrict__ q_out, unsigned short* __restrict__ k_out,
    unsigned short* __restrict__ vt_out) {
  __shared__ __align__(16) unsigned short smem[2 * 16384];
  int z = blockIdx.z;
  const float* X = z == 0 ? x0 : (z == 1 ? x1 : x2);
  const unsigned short* WT = wtb + (size_t)z * D * D;
  const float* B = z == 0 ? b0 : (z == 1 ? b1 : b2);
  float scale = (z == 0) ? SCALE * LOG2E : 1.0f;
  if (z == 2)
    gemm_bt_body<false, 2>(X, WT, B, vt_out, scale, smem);
  else
    gemm_bt_body<false, 1>(X, WT, B, z == 0 ? q_out : k_out, scale, smem);
}

__global__ __launch_bounds__(256, 2) void gemm_oproj(
    const unsigned short* __restrict__ A, const unsigned short* __restrict__ WT,
    const float* __restrict__ B, float* __restrict__ Outp) {
  __shared__ __align__(16) unsigned short smem[2 * 16384];
  gemm_bt_body<true, 0>(A, WT, B, Outp, 1.0f, smem);
}

// ---------------------------------------------------------------------------
// Flash attention v4: UN-PAIRED 1024 blocks (one 64-row q-tile each) so 4
// blocks/CU co-reside (LDS 40 KB x 4 = 160 KB). Per-CU balance via the slot
// permutation: classes {j,j+8,j+16,j+24} -> qt sets summing to 62 phases.
// Softmax reduces tree-shaped (max3-fusable max, pairwise sums) to cut the
// serial dependency chain. Rest as v3. O aliases Q.
// ---------------------------------------------------------------------------
__global__ __launch_bounds__(256, 4) void flash_attn(
    const unsigned short* __restrict__ Q, const unsigned short* __restrict__ K,
    const unsigned short* __restrict__ Vt, unsigned short* __restrict__ O) {
  __shared__ __align__(16) unsigned short k_lds[2][64 * 64];
  __shared__ __align__(16) unsigned short v_lds[2][64 * 64];
  __shared__ __align__(16) unsigned short p_lds[4][16 * 64];

  const int bid = blockIdx.x;
  const int s = bid >> 5, idx = bid & 31;
  const int grp = idx & 7;              // XCD group
  const int bh = grp * 4 + (idx >> 3);  // 4 (b,h) per XCD group
  const int b = bh >> 3, h = bh & 7;
  // balanced slot->qt permutation: each CU's 4 stride-256 slots sum to 62
  const int qt = (s < 8) ? 31 - s : (s < 16) ? s + 8 : (s < 24) ? 31 - s : s - 24;
  const int q0 = qt * 64;

  const int tid = threadIdx.x;
  const int w = tid >> 6, lane = tid & 63;
  const int r = lane & 15, g = lane >> 4;
  const int swz = (r & 7) << 3;

  const unsigned short* Qb = Q + (size_t)b * D + h * NH;
  const unsigned short* Kb = K + (size_t)b * D + h * NH;
  const unsigned short* Vb = Vt + ((size_t)(b * H + h) * NH) * SL;
  unsigned short* Ob = O + (size_t)b * D + h * NH;
  unsigned short* pw = &p_lds[w][0];

  auto STAGE = [&](int kt, int bsel) {
    unsigned short* kl = &k_lds[bsel][0];
    unsigned short* vl = &v_lds[bsel][0];
#pragma unroll
    for (int j = 0; j < 2; ++j) {
      int c = j * 256 + tid;
      int row = c >> 3, c8 = (c & 7) ^ (row & 7);
      gl16(&Kb[(size_t)(kt * 64 + row) * (BS * D) + c8 * 8], &kl[c * 8]);
      gl16(&Vb[(size_t)row * SL + kt * 64 + c8 * 8], &vl[c * 8]);
    }
  };

  STAGE(0, 0);

  short8 qf[2];
#pragma unroll
  for (int kk = 0; kk < 2; ++kk)
    qf[kk] = *reinterpret_cast<const short8*>(
        &Qb[(size_t)(q0 + w * 16 + r) * (BS * D) + kk * 32 + g * 8]);

  f32x4 oa[4];
#pragma unroll
  for (int n = 0; n < 4; ++n) oa[n] = f32x4{0.f, 0.f, 0.f, 0.f};
  float mr = -1e30f, lr = 0.f;

  for (int kt = 0; kt <= qt; ++kt) {
    asm volatile("s_waitcnt vmcnt(0)" ::: "memory");
    __builtin_amdgcn_s_barrier();
    __builtin_amdgcn_sched_barrier(0);
    if (kt + 1 <= qt) STAGE(kt + 1, (kt + 1) & 1);

    const int bsel = kt & 1;
    const unsigned short* kl = &k_lds[bsel][0];
    const unsigned short* vl = &v_lds[bsel][0];
    short8 kf[2][4], vt[2][4];
#pragma unroll
    for (int kk = 0; kk < 2; ++kk)
#pragma unroll
      for (int n = 0; n < 4; ++n)
        kf[kk][n] = *reinterpret_cast<const short8*>(
            &kl[(n * 16 + r) * 64 + (((kk * 4 + g) ^ (r & 7)) * 8)]);

    f32x4 sv[4];
#pragma unroll
    for (int n = 0; n < 4; ++n) sv[n] = f32x4{0.f, 0.f, 0.f, 0.f};
#pragma unroll
    for (int kk = 0; kk < 2; ++kk) {
      __builtin_amdgcn_s_setprio(1);
#pragma unroll
      for (int n = 0; n < 4; ++n)
        sv[n] = __builtin_amdgcn_mfma_f32_16x16x32_bf16(kf[kk][n], qf[kk], sv[n], 0, 0, 0);
      __builtin_amdgcn_s_setprio(0);
    }

#pragma unroll
    for (int kk = 0; kk < 2; ++kk)
#pragma unroll
      for (int n = 0; n < 4; ++n)
        vt[kk][n] = *reinterpret_cast<const short8*>(
            &vl[(n * 16 + r) * 64 + (((kk * 4 + g) ^ (r & 7)) * 8)]);

    if (kt == qt) {
      int qrow = q0 + w * 16 + r;
#pragma unroll
      for (int n = 0; n < 4; ++n)
#pragma unroll
        for (int rr = 0; rr < 4; ++rr)
          if (kt * 64 + n * 16 + g * 4 + rr > qrow) sv[n][rr] = -1e30f;
    }

    // tree max (max3-fusable, depth ~3)
    float t0 = fmaxf(fmaxf(sv[0][0], sv[0][1]), sv[0][2]);
    float t1 = fmaxf(fmaxf(sv[0][3], sv[1][0]), sv[1][1]);
    float t2 = fmaxf(fmaxf(sv[1][2], sv[1][3]), sv[2][0]);
    float t3 = fmaxf(fmaxf(sv[2][1], sv[2][2]), sv[2][3]);
    float t4 = fmaxf(fmaxf(sv[3][0], sv[3][1]), sv[3][2]);
    float mx = fmaxf(fmaxf(fmaxf(t0, t1), fmaxf(t2, t3)), fmaxf(t4, sv[3][3]));
    mx = fmaxf(mx, __shfl_xor(mx, 16));
    mx = fmaxf(mx, __shfl_xor(mx, 32));
    bool need = __any(mx > mr + 8.f);
    float mold = mr;
    float mnew = need ? fmaxf(mold, mx) : mold;
#pragma unroll
    for (int n = 0; n < 4; ++n)
#pragma unroll
      for (int rr = 0; rr < 4; ++rr)
        sv[n][rr] = fast_exp2(sv[n][rr] - mnew);
    // pairwise-tree sum (depth ~4)
    float a0 = (sv[0][0] + sv[0][1]) + (sv[0][2] + sv[0][3]);
    float a1 = (sv[1][0] + sv[1][1]) + (sv[1][2] + sv[1][3]);
    float a2 = (sv[2][0] + sv[2][1]) + (sv[2][2] + sv[2][3]);
    float a3 = (sv[3][0] + sv[3][1]) + (sv[3][2] + sv[3][3]);
    float ps = (a0 + a1) + (a2 + a3);
    ps += __shfl_xor(ps, 16);
    ps += __shfl_xor(ps, 32);
    if (need) {
      float sf = fast_exp2(mold - mnew);
      mr = mnew;
      lr = lr * sf + ps;
#pragma unroll
      for (int n = 0; n < 4; ++n) oa[n] *= sf;
    } else {
      lr += ps;
    }

#pragma unroll
    for (int n = 0; n < 4; ++n) {
      uint2v pk;
      pk.x = cvt_pk_bf16(sv[n][0], sv[n][1]);
      pk.y = cvt_pk_bf16(sv[n][2], sv[n][3]);
      *reinterpret_cast<uint2v*>(&pw[r * 64 + ((n * 16 + g * 4) ^ swz)]) = pk;
    }
    asm volatile("s_waitcnt lgkmcnt(0)" ::: "memory");
    __builtin_amdgcn_sched_barrier(0);

    short8 pf[2];
#pragma unroll
    for (int kk = 0; kk < 2; ++kk)
      pf[kk] = *reinterpret_cast<const short8*>(
          &pw[r * 64 + (((kk * 4 + g) ^ (r & 7)) * 8)]);
#pragma unroll
    for (int kk = 0; kk < 2; ++kk) {
      __builtin_amdgcn_s_setprio(1);
#pragma unroll
      for (int n = 0; n < 4; ++n)
        oa[n] = __builtin_amdgcn_mfma_f32_16x16x32_bf16(vt[kk][n], pf[kk], oa[n], 0, 0, 0);
      __builtin_amdgcn_s_setprio(0);
    }
  }

  // finalize: normalize, transpose via LDS, coalesced stores
  {
    float inv = 1.0f / lr;
#pragma unroll
    for (int n = 0; n < 4; ++n) {
      uint2v pk;
      pk.x = cvt_pk_bf16(oa[n][0] * inv, oa[n][1] * inv);
      pk.y = cvt_pk_bf16(oa[n][2] * inv, oa[n][3] * inv);
      *reinterpret_cast<uint2v*>(&pw[r * 64 + ((n * 16 + g * 4) ^ swz)]) = pk;
    }
    asm volatile("s_waitcnt lgkmcnt(0)" ::: "memory");
    __builtin_amdgcn_sched_barrier(0);
#pragma unroll
    for (int i2 = 0; i2 < 2; ++i2) {
      int c = i2 * 64 + lane;
      int row = c >> 3, c8 = c & 7;
      short8 v = *reinterpret_cast<const short8*>(&pw[row * 64 + c8 * 8]);
      *reinterpret_cast<short8*>(
          &Ob[(size_t)(q0 + w * 16 + row) * (BS * D) + ((c8 ^ (row & 7)) * 8)]) = v;
    }
  }
}

// ---------------------------------------------------------------------------
extern "C" void kernel_launch(void* const* d_in, const int* in_sizes, int n_in,
                              void* d_out, int out_size, void* d_ws, size_t ws_size,
                              hipStream_t stream) {
  const float* x  = (const float*)d_in[0];
  const float* kx = (const float*)d_in[1];
  const float* vx = (const float*)d_in[2];
  const float* Wq = (const float*)d_in[3];
  const float* bq = (const float*)d_in[4];
  const float* Wk = (const float*)d_in[5];
  const float* bk = (const float*)d_in[6];
  const float* Wv = (const float*)d_in[7];
  const float* bv = (const float*)d_in[8];
  const float* Wo = (const float*)d_in[9];
  const float* bo = (const float*)d_in[10];

  // workspace (bf16), 26 MB: qb (attn-out aliases) | kb | vtb | wtb (2 MB)
  unsigned short* ws = (unsigned short*)d_ws;
  unsigned short* qb  = ws;
  unsigned short* kb  = ws + (size_t)M_ROWS * D;
  unsigned short* vtb = ws + (size_t)M_ROWS * D * 2;
  unsigned short* wtb = ws + (size_t)M_ROWS * D * 3;

  prep_wt<<<dim3(256), dim3(256), 0, stream>>>(Wq, Wk, Wv, Wo, wtb);
  qkv_gemm<<<dim3(64, 4, 3), dim3(256), 0, stream>>>(x, kx, vx, wtb, bq, bk, bv,
                                                     qb, kb, vtb);
  flash_attn<<<dim3(1024), dim3(256), 0, stream>>>(qb, kb, vtb, qb);
  gemm_oproj<<<dim3(64, 4, 1), dim3(256), 0, stream>>>(qb, wtb + (size_t)3 * D * D,
                                                       bo, (float*)d_out);
}

// Round 10
// 81.667 us; speedup vs baseline: 3.2669x; 1.0432x over previous
//
#include <hip/hip_runtime.h>

typedef __attribute__((ext_vector_type(8))) short short8;
typedef __attribute__((ext_vector_type(4))) short short4v;
typedef __attribute__((ext_vector_type(4))) float f32x4;
typedef __attribute__((ext_vector_type(2))) unsigned int uint2v;

constexpr int SL = 2048, BS = 4, D = 512, H = 8, NH = 64;
constexpr int M_ROWS = SL * BS;   // 8192
constexpr float SCALE = 0.125f;   // 1/sqrt(64)
constexpr float LOG2E = 1.44269504088896340736f;

__device__ __forceinline__ unsigned short f2bf(float f) {
  union { float f; unsigned u; } v; v.f = f;
  unsigned r = v.u + 0x7FFFu + ((v.u >> 16) & 1u);
  return (unsigned short)(r >> 16);
}

__device__ __forceinline__ unsigned cvt_pk_bf16(float a, float b) {
  unsigned r;
  asm("v_cvt_pk_bf16_f32 %0, %1, %2" : "=v"(r) : "v"(a), "v"(b));
  return r;
}

__device__ __forceinline__ float fast_exp2(float x) {
  float r;
  asm("v_exp_f32 %0, %1" : "=v"(r) : "v"(x));
  return r;
}

// async global->LDS, 16B per lane; LDS dest = wave-uniform base + lane*16
__device__ __forceinline__ void gl16(const void* g, void* l) {
  __builtin_amdgcn_global_load_lds(
      (const __attribute__((address_space(1))) unsigned int*)g,
      (__attribute__((address_space(3))) unsigned int*)l, 16, 0, 0);
}

// ---------------------------------------------------------------------------
// prep: W[512][512] f32 row-major -> W^T[n][k] bf16, LDS-tiled 64x64.
// ---------------------------------------------------------------------------
__global__ __launch_bounds__(256) void prep_wt(
    const float* __restrict__ w0, const float* __restrict__ w1,
    const float* __restrict__ w2, const float* __restrict__ w3,
    unsigned short* __restrict__ wtb) {
  __shared__ float tl[64][65];
  const int tid = threadIdx.x;
  const int wi = blockIdx.x >> 6, t6 = blockIdx.x & 63;
  const int k0 = (t6 >> 3) * 64, n0 = (t6 & 7) * 64;
  const float* W = wi == 0 ? w0 : (wi == 1 ? w1 : (wi == 2 ? w2 : w3));
  unsigned short* WT = wtb + (size_t)wi * D * D;

#pragma unroll
  for (int i = 0; i < 4; ++i) {
    int k = (tid >> 4) + i * 16, n4 = (tid & 15) * 4;
    f32x4 v = *reinterpret_cast<const f32x4*>(&W[(size_t)(k0 + k) * D + n0 + n4]);
#pragma unroll
    for (int j = 0; j < 4; ++j) tl[n4 + j][k] = v[j];
  }
  __syncthreads();
#pragma unroll
  for (int i = 0; i < 2; ++i) {
    int n = (tid >> 3) + i * 32, k8 = (tid & 7) * 8;
    union { unsigned u[4]; short8 s; } pk;
#pragma unroll
    for (int j = 0; j < 4; ++j)
      pk.u[j] = cvt_pk_bf16(tl[n][k8 + 2 * j], tl[n][k8 + 2 * j + 1]);
    *reinterpret_cast<short8*>(&WT[(size_t)(n0 + n) * D + k0 + k8]) = pk.s;
  }
}

// ---------------------------------------------------------------------------
// GEMM v2 (unchanged): double-buffered 2-phase pipeline, counted vmcnt,
// XOR-swizzled LDS, V^T epilogue via LDS bounce.
// ---------------------------------------------------------------------------
template <bool A_BF16, int OUT_MODE>
__device__ __forceinline__ void gemm_bt_body(const void* __restrict__ Ap,
                                             const unsigned short* __restrict__ BT,
                                             const float* __restrict__ bias,
                                             void* __restrict__ Outp, float scale,
                                             unsigned short* smem) {
  const int tid = threadIdx.x;
  const int brow = blockIdx.x * 128;
  const int bcol = blockIdx.y * 128;
  const int lane = tid & 63;
  const int wid = tid >> 6;
  const int wr = (wid >> 1) * 64;
  const int wc = (wid & 1) * 64;
  const int r = lane & 15;
  const int g = lane >> 4;

  auto a_buf = [&](int b) { return smem + b * 16384; };
  auto b_buf = [&](int b) { return smem + b * 16384 + 8192; };

  f32x4 acc[4][4];
#pragma unroll
  for (int m = 0; m < 4; ++m)
#pragma unroll
    for (int n = 0; n < 4; ++n) acc[m][n] = f32x4{0.f, 0.f, 0.f, 0.f};

  auto STAGE_B = [&](int kt, int bsel) {
    unsigned short* bl = b_buf(bsel);
#pragma unroll
    for (int j = 0; j < 4; ++j) {
      int c = j * 256 + tid;
      int row = c >> 3, c8 = (c & 7) ^ (row & 7);
      gl16(&BT[(size_t)(bcol + row) * D + kt + c8 * 8], &bl[c * 8]);
    }
  };
  auto STAGE_A_LDS = [&](int kt, int bsel) {
    const unsigned short* A = (const unsigned short*)Ap;
    unsigned short* al = a_buf(bsel);
#pragma unroll
    for (int j = 0; j < 4; ++j) {
      int c = j * 256 + tid;
      int row = c >> 3, c8 = (c & 7) ^ (row & 7);
      gl16(&A[(size_t)(brow + row) * D + kt + c8 * 8], &al[c * 8]);
    }
  };
  auto A_LOAD = [&](int kt, f32x4 (&va)[4][2]) {
    const float* A = (const float*)Ap;
#pragma unroll
    for (int j = 0; j < 4; ++j) {
      int c = j * 256 + tid;
      int row = c >> 3, c8 = (c & 7) ^ (row & 7);
      const float* ap = &A[(size_t)(brow + row) * D + kt + c8 * 8];
      va[j][0] = *reinterpret_cast<const f32x4*>(ap);
      va[j][1] = *reinterpret_cast<const f32x4*>(ap + 4);
    }
  };
  auto A_WRITE = [&](f32x4 (&va)[4][2], int bsel) {
    unsigned short* al = a_buf(bsel);
#pragma unroll
    for (int j = 0; j < 4; ++j) {
      int c = j * 256 + tid;
      union { unsigned u[4]; short8 s; } pk;
      pk.u[0] = cvt_pk_bf16(va[j][0][0], va[j][0][1]);
      pk.u[1] = cvt_pk_bf16(va[j][0][2], va[j][0][3]);
      pk.u[2] = cvt_pk_bf16(va[j][1][0], va[j][1][1]);
      pk.u[3] = cvt_pk_bf16(va[j][1][2], va[j][1][3]);
      *reinterpret_cast<short8*>(&al[c * 8]) = pk.s;
    }
  };
  auto COMPUTE = [&](int bsel) {
    const unsigned short* al = a_buf(bsel);
    const unsigned short* bl = b_buf(bsel);
#pragma unroll
    for (int kk2 = 0; kk2 < 2; ++kk2) {
      short8 af[4], bfr[4];
#pragma unroll
      for (int m = 0; m < 4; ++m)
        af[m] = *reinterpret_cast<const short8*>(
            &al[(wr + m * 16 + r) * 64 + (((kk2 * 4 + g) ^ (r & 7)) * 8)]);
#pragma unroll
      for (int n = 0; n < 4; ++n)
        bfr[n] = *reinterpret_cast<const short8*>(
            &bl[(wc + n * 16 + r) * 64 + (((kk2 * 4 + g) ^ (r & 7)) * 8)]);
      __builtin_amdgcn_s_setprio(1);
#pragma unroll
      for (int m = 0; m < 4; ++m)
#pragma unroll
        for (int n = 0; n < 4; ++n)
          acc[m][n] = __builtin_amdgcn_mfma_f32_16x16x32_bf16(af[m], bfr[n], acc[m][n], 0, 0, 0);
      __builtin_amdgcn_s_setprio(0);
    }
  };

  if (A_BF16) {
    STAGE_A_LDS(0, 0);
    STAGE_B(0, 0);
    asm volatile("s_waitcnt vmcnt(0)" ::: "memory");
  } else {
    f32x4 va[4][2];
    A_LOAD(0, va);
    STAGE_B(0, 0);
    asm volatile("s_waitcnt vmcnt(4)" ::: "memory");
    A_WRITE(va, 0);
    asm volatile("s_waitcnt vmcnt(0) lgkmcnt(0)" ::: "memory");
  }
  __builtin_amdgcn_s_barrier();

#pragma unroll
  for (int t = 0; t < 8; ++t) {
    const int cur = t & 1, nxt = cur ^ 1;
    const int ktn = (t + 1) * 64;
    __builtin_amdgcn_sched_barrier(0);
    f32x4 va[4][2];
    if (t < 7) {
      if (A_BF16) {
        STAGE_A_LDS(ktn, nxt);
        STAGE_B(ktn, nxt);
      } else {
        A_LOAD(ktn, va);
        STAGE_B(ktn, nxt);
      }
    }
    __builtin_amdgcn_sched_barrier(0);
    COMPUTE(cur);
    if (t < 7) {
      if (!A_BF16) {
        asm volatile("s_waitcnt vmcnt(4)" ::: "memory");
        A_WRITE(va, nxt);
      }
      asm volatile("s_waitcnt vmcnt(0) lgkmcnt(0)" ::: "memory");
      __builtin_amdgcn_s_barrier();
    }
  }

  if (OUT_MODE == 2) {
    unsigned short* sc = smem;
    const int wr4 = wr >> 2;
#pragma unroll
    for (int m = 0; m < 4; ++m)
#pragma unroll
      for (int n = 0; n < 4; ++n) {
        int col = wc + n * 16 + r;
        float bv = bias[bcol + col];
        int sl = wr4 + m * 4 + g;
#pragma unroll
        for (int rr = 0; rr < 4; ++rr) {
          int c = (rr * 4 + (sl >> 3)) ^ (col & 7);
          sc[col * 128 + c * 8 + (sl & 7)] = f2bf((acc[m][n][rr] + bv) * scale);
        }
      }
    asm volatile("s_waitcnt lgkmcnt(0)" ::: "memory");
    __builtin_amdgcn_s_barrier();
    unsigned short* VT = (unsigned short*)Outp;
#pragma unroll
    for (int i2 = 0; i2 < 2; ++i2) {
      int q = tid * 2 + i2;
      int col = q >> 2, bb = q & 3;
      int gcol = bcol + col, hh = gcol >> 6, nh = gcol & 63;
      size_t gbase = (((size_t)bb * H + hh) * NH + nh) * SL + (brow >> 2);
#pragma unroll
      for (int j = 0; j < 4; ++j) {
        short8 v = *reinterpret_cast<const short8*>(
            &sc[col * 128 + (((bb * 4 + j) ^ (col & 7)) * 8)]);
        *reinterpret_cast<short8*>(&VT[gbase + j * 8]) = v;
      }
    }
  } else {
#pragma unroll
    for (int m = 0; m < 4; ++m)
#pragma unroll
      for (int n = 0; n < 4; ++n) {
        int gcol = bcol + wc + n * 16 + r;
        float bv = bias[gcol];
#pragma unroll
        for (int rr = 0; rr < 4; ++rr) {
          int grow = brow + wr + m * 16 + g * 4 + rr;
          float val = (acc[m][n][rr] + bv) * scale;
          if (OUT_MODE == 0)
            ((float*)Outp)[(size_t)grow * D + gcol] = val;
          else
            ((unsigned short*)Outp)[(size_t)grow * D + gcol] = f2bf(val);
        }
      }
  }
}

__global__ __launch_bounds__(256, 2) void qkv_gemm(
    const float* __restrict__ x0, const float* __restrict__ x1, const float* __restrict__ x2,
    const unsigned short* __restrict__ wtb,
    const float* __restrict__ b0, const float* __restrict__ b1, const float* __restrict__ b2,
    unsigned short* __restrict__ q_out, unsigned short* __restrict__ k_out,
    unsigned short* __restrict__ vt_out) {
  __shared__ __align__(16) unsigned short smem[2 * 16384];
  int z = blockIdx.z;
  const float* X = z == 0 ? x0 : (z == 1 ? x1 : x2);
  const unsigned short* WT = wtb + (size_t)z * D * D;
  const float* B = z == 0 ? b0 : (z == 1 ? b1 : b2);
  float scale = (z == 0) ? SCALE * LOG2E : 1.0f;
  if (z == 2)
    gemm_bt_body<false, 2>(X, WT, B, vt_out, scale, smem);
  else
    gemm_bt_body<false, 1>(X, WT, B, z == 0 ? q_out : k_out, scale, smem);
}

__global__ __launch_bounds__(256, 2) void gemm_oproj(
    const unsigned short* __restrict__ A, const unsigned short* __restrict__ WT,
    const float* __restrict__ B, float* __restrict__ Outp) {
  __shared__ __align__(16) unsigned short smem[2 * 16384];
  gemm_bt_body<true, 0>(A, WT, B, Outp, 1.0f, smem);
}

// ---------------------------------------------------------------------------
// Flash attention v5: v4 structure + shuffle-free common path.
//  - lazy max-reduce: __any() on the PER-LANE partial max decides "need";
//    cross-lane max shuffles run only when the running max must move.
//  - deferred l-reduction: per-lane partial lrp, cross-lane reduced ONCE at
//    finalize (l never gates P/PV within a phase).
// ---------------------------------------------------------------------------
__global__ __launch_bounds__(256, 4) void flash_attn(
    const unsigned short* __restrict__ Q, const unsigned short* __restrict__ K,
    const unsigned short* __restrict__ Vt, unsigned short* __restrict__ O) {
  __shared__ __align__(16) unsigned short k_lds[2][64 * 64];
  __shared__ __align__(16) unsigned short v_lds[2][64 * 64];
  __shared__ __align__(16) unsigned short p_lds[4][16 * 64];

  const int bid = blockIdx.x;
  const int s = bid >> 5, idx = bid & 31;
  const int grp = idx & 7;              // XCD group
  const int bh = grp * 4 + (idx >> 3);  // 4 (b,h) per XCD group
  const int b = bh >> 3, h = bh & 7;
  // balanced slot->qt permutation: each CU's 4 stride-256 slots sum to 62
  const int qt = (s < 8) ? 31 - s : (s < 16) ? s + 8 : (s < 24) ? 31 - s : s - 24;
  const int q0 = qt * 64;

  const int tid = threadIdx.x;
  const int w = tid >> 6, lane = tid & 63;
  const int r = lane & 15, g = lane >> 4;
  const int swz = (r & 7) << 3;

  const unsigned short* Qb = Q + (size_t)b * D + h * NH;
  const unsigned short* Kb = K + (size_t)b * D + h * NH;
  const unsigned short* Vb = Vt + ((size_t)(b * H + h) * NH) * SL;
  unsigned short* Ob = O + (size_t)b * D + h * NH;
  unsigned short* pw = &p_lds[w][0];

  auto STAGE = [&](int kt, int bsel) {
    unsigned short* kl = &k_lds[bsel][0];
    unsigned short* vl = &v_lds[bsel][0];
#pragma unroll
    for (int j = 0; j < 2; ++j) {
      int c = j * 256 + tid;
      int row = c >> 3, c8 = (c & 7) ^ (row & 7);
      gl16(&Kb[(size_t)(kt * 64 + row) * (BS * D) + c8 * 8], &kl[c * 8]);
      gl16(&Vb[(size_t)row * SL + kt * 64 + c8 * 8], &vl[c * 8]);
    }
  };

  STAGE(0, 0);

  short8 qf[2];
#pragma unroll
  for (int kk = 0; kk < 2; ++kk)
    qf[kk] = *reinterpret_cast<const short8*>(
        &Qb[(size_t)(q0 + w * 16 + r) * (BS * D) + kk * 32 + g * 8]);

  f32x4 oa[4];
#pragma unroll
  for (int n = 0; n < 4; ++n) oa[n] = f32x4{0.f, 0.f, 0.f, 0.f};
  float mr = -1e30f, lrp = 0.f;   // lrp: per-lane partial denominator

  for (int kt = 0; kt <= qt; ++kt) {
    asm volatile("s_waitcnt vmcnt(0)" ::: "memory");
    __builtin_amdgcn_s_barrier();
    __builtin_amdgcn_sched_barrier(0);
    if (kt + 1 <= qt) STAGE(kt + 1, (kt + 1) & 1);

    const int bsel = kt & 1;
    const unsigned short* kl = &k_lds[bsel][0];
    const unsigned short* vl = &v_lds[bsel][0];
    short8 kf[2][4], vt[2][4];
#pragma unroll
    for (int kk = 0; kk < 2; ++kk)
#pragma unroll
      for (int n = 0; n < 4; ++n)
        kf[kk][n] = *reinterpret_cast<const short8*>(
            &kl[(n * 16 + r) * 64 + (((kk * 4 + g) ^ (r & 7)) * 8)]);

    f32x4 sv[4];
#pragma unroll
    for (int n = 0; n < 4; ++n) sv[n] = f32x4{0.f, 0.f, 0.f, 0.f};
#pragma unroll
    for (int kk = 0; kk < 2; ++kk) {
      __builtin_amdgcn_s_setprio(1);
#pragma unroll
      for (int n = 0; n < 4; ++n)
        sv[n] = __builtin_amdgcn_mfma_f32_16x16x32_bf16(kf[kk][n], qf[kk], sv[n], 0, 0, 0);
      __builtin_amdgcn_s_setprio(0);
    }

#pragma unroll
    for (int kk = 0; kk < 2; ++kk)
#pragma unroll
      for (int n = 0; n < 4; ++n)
        vt[kk][n] = *reinterpret_cast<const short8*>(
            &vl[(n * 16 + r) * 64 + (((kk * 4 + g) ^ (r & 7)) * 8)]);

    if (kt == qt) {
      int qrow = q0 + w * 16 + r;
#pragma unroll
      for (int n = 0; n < 4; ++n)
#pragma unroll
        for (int rr = 0; rr < 4; ++rr)
          if (kt * 64 + n * 16 + g * 4 + rr > qrow) sv[n][rr] = -1e30f;
    }

    // in-lane max (tree, max3-fusable) -> lazy cross-lane reduce
    float t0 = fmaxf(fmaxf(sv[0][0], sv[0][1]), sv[0][2]);
    float t1 = fmaxf(fmaxf(sv[0][3], sv[1][0]), sv[1][1]);
    float t2 = fmaxf(fmaxf(sv[1][2], sv[1][3]), sv[2][0]);
    float t3 = fmaxf(fmaxf(sv[2][1], sv[2][2]), sv[2][3]);
    float t4 = fmaxf(fmaxf(sv[3][0], sv[3][1]), sv[3][2]);
    float mxl = fmaxf(fmaxf(fmaxf(t0, t1), fmaxf(t2, t3)), fmaxf(t4, sv[3][3]));
    bool need = __any(mxl > mr + 8.f);
    float mold = mr;
    float mnew = mold;
    if (need) {
      float mx = fmaxf(mxl, __shfl_xor(mxl, 16));
      mx = fmaxf(mx, __shfl_xor(mx, 32));
      mnew = fmaxf(mold, mx);
    }
#pragma unroll
    for (int n = 0; n < 4; ++n)
#pragma unroll
      for (int rr = 0; rr < 4; ++rr)
        sv[n][rr] = fast_exp2(sv[n][rr] - mnew);
    // per-lane partial sum only (cross-lane deferred to finalize)
    float a0 = (sv[0][0] + sv[0][1]) + (sv[0][2] + sv[0][3]);
    float a1 = (sv[1][0] + sv[1][1]) + (sv[1][2] + sv[1][3]);
    float a2 = (sv[2][0] + sv[2][1]) + (sv[2][2] + sv[2][3]);
    float a3 = (sv[3][0] + sv[3][1]) + (sv[3][2] + sv[3][3]);
    float psl = (a0 + a1) + (a2 + a3);
    if (need) {
      float sf = fast_exp2(mold - mnew);
      mr = mnew;
      lrp = lrp * sf + psl;
#pragma unroll
      for (int n = 0; n < 4; ++n) oa[n] *= sf;
    } else {
      lrp += psl;
    }

#pragma unroll
    for (int n = 0; n < 4; ++n) {
      uint2v pk;
      pk.x = cvt_pk_bf16(sv[n][0], sv[n][1]);
      pk.y = cvt_pk_bf16(sv[n][2], sv[n][3]);
      *reinterpret_cast<uint2v*>(&pw[r * 64 + ((n * 16 + g * 4) ^ swz)]) = pk;
    }
    asm volatile("s_waitcnt lgkmcnt(0)" ::: "memory");
    __builtin_amdgcn_sched_barrier(0);

    short8 pf[2];
#pragma unroll
    for (int kk = 0; kk < 2; ++kk)
      pf[kk] = *reinterpret_cast<const short8*>(
          &pw[r * 64 + (((kk * 4 + g) ^ (r & 7)) * 8)]);
#pragma unroll
    for (int kk = 0; kk < 2; ++kk) {
      __builtin_amdgcn_s_setprio(1);
#pragma unroll
      for (int n = 0; n < 4; ++n)
        oa[n] = __builtin_amdgcn_mfma_f32_16x16x32_bf16(vt[kk][n], pf[kk], oa[n], 0, 0, 0);
      __builtin_amdgcn_s_setprio(0);
    }
  }

  // finalize: reduce lrp across the 4 g-groups ONCE, normalize, store
  {
    float lr = lrp + __shfl_xor(lrp, 16);
    lr += __shfl_xor(lr, 32);
    float inv = 1.0f / lr;
#pragma unroll
    for (int n = 0; n < 4; ++n) {
      uint2v pk;
      pk.x = cvt_pk_bf16(oa[n][0] * inv, oa[n][1] * inv);
      pk.y = cvt_pk_bf16(oa[n][2] * inv, oa[n][3] * inv);
      *reinterpret_cast<uint2v*>(&pw[r * 64 + ((n * 16 + g * 4) ^ swz)]) = pk;
    }
    asm volatile("s_waitcnt lgkmcnt(0)" ::: "memory");
    __builtin_amdgcn_sched_barrier(0);
#pragma unroll
    for (int i2 = 0; i2 < 2; ++i2) {
      int c = i2 * 64 + lane;
      int row = c >> 3, c8 = c & 7;
      short8 v = *reinterpret_cast<const short8*>(&pw[row * 64 + c8 * 8]);
      *reinterpret_cast<short8*>(
          &Ob[(size_t)(q0 + w * 16 + row) * (BS * D) + ((c8 ^ (row & 7)) * 8)]) = v;
    }
  }
}

// ---------------------------------------------------------------------------
extern "C" void kernel_launch(void* const* d_in, const int* in_sizes, int n_in,
                              void* d_out, int out_size, void* d_ws, size_t ws_size,
                              hipStream_t stream) {
  const float* x  = (const float*)d_in[0];
  const float* kx = (const float*)d_in[1];
  const float* vx = (const float*)d_in[2];
  const float* Wq = (const float*)d_in[3];
  const float* bq = (const float*)d_in[4];
  const float* Wk = (const float*)d_in[5];
  const float* bk = (const float*)d_in[6];
  const float* Wv = (const float*)d_in[7];
  const float* bv = (const float*)d_in[8];
  const float* Wo = (const float*)d_in[9];
  const float* bo = (const float*)d_in[10];

  // workspace (bf16), 26 MB: qb (attn-out aliases) | kb | vtb | wtb (2 MB)
  unsigned short* ws = (unsigned short*)d_ws;
  unsigned short* qb  = ws;
  unsigned short* kb  = ws + (size_t)M_ROWS * D;
  unsigned short* vtb = ws + (size_t)M_ROWS * D * 2;
  unsigned short* wtb = ws + (size_t)M_ROWS * D * 3;

  prep_wt<<<dim3(256), dim3(256), 0, stream>>>(Wq, Wk, Wv, Wo, wtb);
  qkv_gemm<<<dim3(64, 4, 3), dim3(256), 0, stream>>>(x, kx, vx, wtb, bq, bk, bv,
                                                     qb, kb, vtb);
  flash_attn<<<dim3(1024), dim3(256), 0, stream>>>(qb, kb, vtb, qb);
  gemm_oproj<<<dim3(64, 4, 1), dim3(256), 0, stream>>>(qb, wtb + (size_t)3 * D * D,
                                                       bo, (float*)d_out);
}